// Round 7
// baseline (109.280 us; speedup 1.0000x reference)
//
#include <hip/hip_runtime.h>
#include <math.h>

constexpr int Bn = 512;      // batch
constexpr int Dn = 16384;    // priors
constexpr int BS = 512;      // select-kernel block size (8 waves)
constexpr int CHUNKS = 4;
constexpr int CPRI = Dn / CHUNKS;  // 4096 priors per chunk
constexpr int K1T = 256;           // stream-kernel threads
constexpr int TILE = 1024;         // priors per staged tile (12 KB conf)
constexpr int NT = CPRI / TILE;    // 4 tiles per block

__device__ __forceinline__ float lse3(float a, float b, float c) {
  float m = fmaxf(a, fmaxf(b, c));
  return m + __logf(__expf(a - m) + __expf(b - m) + __expf(c - m));
}
__device__ __forceinline__ float sl1f(float x) {
  float a = fabsf(x);
  return a < 1.f ? 0.5f * x * x : a - 0.5f;
}

// ln(s) for s in (1,3], 0 TRANS: ln(s) = ln2 + ln1p(w), w = s/2-1 in (-0.5,0.5]
// degree-9 Taylor/Horner, abs err ~1e-4 (<< 5e-2 output tolerance)
__device__ __forceinline__ float ln_s(float s) {
  float w = __fmaf_rn(0.5f, s, -1.0f);
  float h = __fmaf_rn(w, 1.f / 9.f, -0.125f);
  h = __fmaf_rn(w, h, 1.f / 7.f);
  h = __fmaf_rn(w, h, -1.f / 6.f);
  h = __fmaf_rn(w, h, 0.2f);
  h = __fmaf_rn(w, h, -0.25f);
  h = __fmaf_rn(w, h, 1.f / 3.f);
  h = __fmaf_rn(w, h, -0.5f);
  h = __fmaf_rn(w, h, 1.0f);
  return __fmaf_rn(w, h, 0.69314718055994531f);
}

__device__ __forceinline__ double blockReduceAddD(double v, double* sred) {
  int t = threadIdx.x;
  sred[t] = v;
  __syncthreads();
  for (int off = BS >> 1; off > 0; off >>= 1) {
    if (t < off) sred[t] += sred[t + off];
    __syncthreads();
  }
  double r = sred[0];
  __syncthreads();
  return r;
}

// ============================ K1: streaming (DMA staging + 2-TRANS math) ============================
__global__ __launch_bounds__(K1T) void multiloss_stream(
    const float* __restrict__ loc_pred, const float* __restrict__ conf_pred,
    const float* __restrict__ targets, const float* __restrict__ default_bar,
    float* __restrict__ lc,
    float* __restrict__ pce, float* __restrict__ plloc, int* __restrict__ pnpos,
    float* __restrict__ pbv, int* __restrict__ pbi)
{
  __shared__ float s_conf[2][TILE * 3];   // 2 x 12 KB double buffer
  __shared__ float s_a[4]; __shared__ float s_b[4]; __shared__ int s_c[4];
  __shared__ float s_vi[4]; __shared__ float s_vu[4]; __shared__ int s_i[4];

  const int bid = blockIdx.x;
  const int b = bid >> 2, c = bid & 3;
  const int t = threadIdx.x;

  const float t0 = targets[b * 3 + 0];
  const float t1 = targets[b * 3 + 1];
  const int   lab = (int)targets[b * 3 + 2];

  const float4* __restrict__ cp4 =
      (const float4*)(conf_pred + (size_t)b * Dn * 3) + (size_t)c * (CPRI * 3 / 4);
  const float2* __restrict__ bar2 = (const float2*)default_bar;
  const float2* __restrict__ lp2  = (const float2*)loc_pred + (size_t)b * Dn;
  float* __restrict__ lcrow = lc + (size_t)b * Dn;

  const int wbase = t & ~63;

  auto stage = [&](int buf, int tile) {
    const float4* src = cp4 + (size_t)tile * (TILE * 3 / 4);
    float4* dst = (float4*)s_conf[buf];
    #pragma unroll
    for (int j = 0; j < 3; ++j) {
      __builtin_amdgcn_global_load_lds(
          (const __attribute__((address_space(1))) void*)(src + j * 256 + t),
          (__attribute__((address_space(3))) void*)(dst + j * 256 + wbase),
          16, 0, 0);
    }
  };

  float ce = 0.f, lloc = 0.f; int npos = 0;
  // argmax state: ratio = bInter/bUni, compared by cross-multiplication
  float bInter = -1.f, bUni = 1.f; int bestI = 0;
  const float m_c = (t0 + t1) * 0.5f;
  const float m_l = t1 - t0;
  const float log_ml = __logf(m_l);   // hoisted: 1 TRANS per block

  int cur = 0;
  stage(0, 0);
  __syncthreads();

  for (int tile = 0; tile < NT; ++tile) {
    if (tile + 1 < NT) stage(cur ^ 1, tile + 1);
    const float* sc = s_conf[cur];
    const int pbase = c * CPRI + tile * TILE;

    if (lab == 0) {
      #pragma unroll
      for (int i = 0; i < TILE / K1T; ++i) {
        int p = i * K1T + t;
        float c0 = sc[3 * p], c1 = sc[3 * p + 1], c2 = sc[3 * p + 2];
        float hi = fmaxf(c0, c1), lo = fminf(c0, c1);
        float m  = fmaxf(hi, c2), mid = fminf(hi, c2);
        float s  = 1.0f + __expf(lo - m) + __expf(mid - m);   // 2 TRANS
        ce += (m - c0) + ln_s(s);
      }
    } else {
      #pragma unroll
      for (int i = 0; i < TILE / K1T; ++i) {
        int p = i * K1T + t;
        int g = pbase + p;
        float c0 = sc[3 * p], c1 = sc[3 * p + 1], c2 = sc[3 * p + 2];
        float hi = fmaxf(c0, c1), lo = fminf(c0, c1);
        float m  = fmaxf(hi, c2), mid = fminf(hi, c2);
        float s  = 1.0f + __expf(lo - m) + __expf(mid - m);   // 2 TRANS
        float lnS = ln_s(s);

        float2 db = bar2[g];
        float d_c = db.x, d_l = db.y;
        float d_s = d_c - d_l * 0.5f;
        float d_e = d_c + d_l * 0.5f;
        float inter = fmaxf(fminf(t1, d_e) - fmaxf(t0, d_s), 0.f);
        float uni = (t1 - t0) + (d_e - d_s) - inter;

        // argmax(inter/uni) via cross-mult (div-free, monotone in true ratio)
        float lhs = inter * bUni, rhs = bInter * uni;
        if (lhs > rhs || (lhs == rhs && g < bestI)) { bInter = inter; bUni = uni; bestI = g; }

        float lcv;
        if (2.f * inter >= uni) {   // exact sign test == (inter/uni >= 0.5)
          npos++;
          float cl = (lab == 1) ? c1 : c2;
          ce += (m - cl) + lnS;
          float2 lp = lp2[g];
          float pd0 = lp.x - __fdividef(m_c - d_c, d_l);
          float pd1 = (lp.y - log_ml) + __logf(d_l);
          lloc += sl1f(pd0) + sl1f(pd1);
          lcv = 0.f;
        } else {
          lcv = (m - c0) + lnS;
        }
        lcrow[g] = lcv;
      }
    }
    __syncthreads();
    cur ^= 1;
  }

  // wave butterfly reduce (width 64)
  #pragma unroll
  for (int off = 1; off < 64; off <<= 1) {
    ce   += __shfl_xor(ce, off);
    lloc += __shfl_xor(lloc, off);
    npos += __shfl_xor(npos, off);
    float oI = __shfl_xor(bInter, off);
    float oU = __shfl_xor(bUni, off);
    int   oX = __shfl_xor(bestI, off);
    float lhs = oI * bUni, rhs = bInter * oU;
    if (lhs > rhs || (lhs == rhs && oX < bestI)) { bInter = oI; bUni = oU; bestI = oX; }
  }
  const int w = t >> 6;
  if ((t & 63) == 0) { s_a[w] = ce; s_b[w] = lloc; s_c[w] = npos; s_vi[w] = bInter; s_vu[w] = bUni; s_i[w] = bestI; }
  __syncthreads();
  if (t == 0) {
    float Ce = s_a[0], Ll = s_b[0]; int Np = s_c[0];
    float Bi = s_vi[0], Bu = s_vu[0]; int Bx = s_i[0];
    for (int k = 1; k < 4; ++k) {
      Ce += s_a[k]; Ll += s_b[k]; Np += s_c[k];
      float lhs = s_vi[k] * Bu, rhs = Bi * s_vu[k];
      if (lhs > rhs || (lhs == rhs && s_i[k] < Bx)) { Bi = s_vi[k]; Bu = s_vu[k]; Bx = s_i[k]; }
    }
    int pidx = b * CHUNKS + c;
    pce[pidx] = Ce; plloc[pidx] = Ll; pnpos[pidx] = Np;
    pbv[pidx] = Bi / Bu;   // one exact division per chunk == ref's ov[best]
    pbi[pidx] = Bx;
  }
}

// ============================ K2: per-row select ============================
__global__ __launch_bounds__(BS) void multiloss_select(
    const float* __restrict__ loc_pred, const float* __restrict__ conf_pred,
    const float* __restrict__ targets, const float* __restrict__ default_bar,
    const float* __restrict__ lc,
    const float* __restrict__ pce, const float* __restrict__ plloc,
    const int* __restrict__ pnpos, const float* __restrict__ pbv, const int* __restrict__ pbi,
    double* __restrict__ rloc, double* __restrict__ rconf, double* __restrict__ rnp)
{
  __shared__ float    s_lc[Dn];        // 64 KB
  __shared__ int      s_hist[2048];    // 8 KB
  __shared__ double   s_dred[BS];      // 4 KB
  __shared__ unsigned s_wt[8];
  __shared__ unsigned s_sel[2];
  __shared__ double   s_sc[2];
  __shared__ int      s_np;

  const int b = blockIdx.x;
  const int t = threadIdx.x;
  const int lab = (int)targets[b * 3 + 2];

  if (lab == 0) {
    if (t == 0) {
      double ce = (double)pce[4 * b] + (double)pce[4 * b + 1]
                + (double)pce[4 * b + 2] + (double)pce[4 * b + 3];
      rloc[b] = 0.0; rconf[b] = ce; rnp[b] = (double)Dn;
    }
    return;
  }

  const float4* lcr = (const float4*)(lc + (size_t)b * Dn);
  float4* sl4 = (float4*)s_lc;
  #pragma unroll
  for (int j = 0; j < Dn / 4 / BS; ++j) sl4[j * BS + t] = lcr[j * BS + t];
  __syncthreads();

  if (t == 0) {
    const float t0 = targets[b * 3 + 0];
    const float t1 = targets[b * 3 + 1];
    double ce = 0.0, ll = 0.0; int np = 0;
    float bV = -1.f; int bI = 0;
    for (int k = 0; k < 4; ++k) {
      int pi = 4 * b + k;
      ce += (double)pce[pi]; ll += (double)plloc[pi]; np += pnpos[pi];
      float v = pbv[pi]; int i2 = pbi[pi];
      if (v > bV || (v == bV && i2 < bI)) { bV = v; bI = i2; }
    }
    if (bV < 0.5f) {
      int d = bI;
      const float* cp = conf_pred + (size_t)b * Dn * 3 + (size_t)d * 3;
      float c0 = cp[0], c1 = cp[1], c2 = cp[2];
      float lse = lse3(c0, c1, c2);
      float cl = (lab == 1) ? c1 : c2;
      ce += (double)(lse - cl);
      float2 db = ((const float2*)default_bar)[d];
      float2 lp = ((const float2*)loc_pred)[(size_t)b * Dn + d];
      float m_c = (t0 + t1) * 0.5f, m_l = t1 - t0;
      float pd0 = lp.x - (m_c - db.x) / db.y;
      float pd1 = lp.y - __logf(m_l / db.y);
      ll += (double)(sl1f(pd0) + sl1f(pd1));
      np += 1;
      s_lc[d] = 0.f;
    }
    s_sc[0] = ce; s_sc[1] = ll; s_np = np;
  }
  __syncthreads();
  const int np = s_np;
  const int k = min(3 * np, Dn - 1);

  unsigned prefix = 0;
  int K = k;
  const int lane = t & 63, w = t >> 6;
  for (int r = 0; r < 3; ++r) {
    for (int i = t; i < 2048; i += BS) s_hist[i] = 0;
    __syncthreads();
    for (int d = t; d < Dn; d += BS) {
      unsigned u = __float_as_uint(s_lc[d]);
      bool ok = (r == 0) || (r == 1 ? ((u >> 21) == prefix) : ((u >> 10) == prefix));
      if (ok) {
        unsigned bin = (r == 0) ? (u >> 21)
                     : (r == 1) ? ((u >> 10) & 0x7FFu)
                                : (u & 0x3FFu);
        atomicAdd(&s_hist[bin], 1);
      }
    }
    __syncthreads();
    const int nb  = (r == 2) ? 1024 : 2048;
    const int per = nb / BS;
    unsigned psum = 0;
    const int basebin = t * per;
    for (int j = 0; j < per; ++j) psum += (unsigned)s_hist[basebin + j];
    unsigned incl = psum;
    #pragma unroll
    for (int off = 1; off < 64; off <<= 1) {
      unsigned v = __shfl_down(incl, off, 64);
      if (lane + off < 64) incl += v;
    }
    if (lane == 0) s_wt[w] = incl;
    __syncthreads();
    unsigned aboveW = 0;
    for (int w2 = w + 1; w2 < 8; ++w2) aboveW += s_wt[w2];
    const unsigned above = aboveW + (incl - psum);
    if (above < (unsigned)K && (unsigned)K <= above + psum) {
      unsigned cum = above;
      int found = 0;
      for (int j = per - 1; j >= 0; --j) {
        unsigned cnt = (unsigned)s_hist[basebin + j];
        if (cum + cnt >= (unsigned)K) { found = j; break; }
        cum += cnt;
      }
      s_sel[0] = (unsigned)(basebin + found);
      s_sel[1] = cum;
    }
    __syncthreads();
    unsigned selBin = s_sel[0];
    K -= (int)s_sel[1];
    prefix = (r == 0) ? selBin
           : (r == 1) ? ((prefix << 11) | selBin)
                      : ((prefix << 10) | selBin);
    __syncthreads();
  }
  const unsigned tb = prefix;

  float    ssum = 0.f;
  unsigned scnt = 0;
  for (int d = t; d < Dn; d += BS) {
    float v = s_lc[d];
    if (__float_as_uint(v) > tb) { ssum += v; scnt++; }
  }
  double S = blockReduceAddD((double)ssum, s_dred);
  double C = blockReduceAddD((double)scnt, s_dred);

  if (t == 0) {
    double tval = (double)__uint_as_float(tb);
    double topk = S + ((double)k - C) * tval;
    rloc[b]  = s_sc[1];
    rconf[b] = s_sc[0] + topk;
    rnp[b]   = (double)np;
  }
}

// ============================ probes (diagnostic; outputs to ws) ============================
// P1: 12 independent register loads/thread, pure read of conf (100 MB)
__global__ __launch_bounds__(K1T) void probe_reg12(const float4* __restrict__ src,
                                                   float* __restrict__ dst) {
  const int bid = blockIdx.x, t = threadIdx.x;
  const float4* p = src + (size_t)bid * 3072;
  float4 v[12];
  #pragma unroll
  for (int j = 0; j < 12; ++j) v[j] = p[j * 256 + t];
  float acc = 0.f;
  #pragma unroll
  for (int j = 0; j < 12; ++j) acc += v[j].x + v[j].y + v[j].z + v[j].w;
  #pragma unroll
  for (int off = 1; off < 64; off <<= 1) acc += __shfl_xor(acc, off);
  if ((t & 63) == 0) dst[bid * 4 + (t >> 6)] = acc;
}

// P2: 12 global_load_lds DMA loads/thread (guaranteed 12-deep MLP), pure read
__global__ __launch_bounds__(K1T) void probe_dma12(const float4* __restrict__ src,
                                                   float* __restrict__ dst) {
  __shared__ float4 buf[3072];   // 48 KB
  const int bid = blockIdx.x, t = threadIdx.x;
  const float4* p = src + (size_t)bid * 3072;
  const int wbase = t & ~63;
  #pragma unroll
  for (int j = 0; j < 12; ++j)
    __builtin_amdgcn_global_load_lds(
        (const __attribute__((address_space(1))) void*)(p + j * 256 + t),
        (__attribute__((address_space(3))) void*)(buf + j * 256 + wbase), 16, 0, 0);
  __syncthreads();
  float acc = 0.f;
  #pragma unroll
  for (int j = 0; j < 12; ++j) { float4 v = buf[j * 256 + t]; acc += v.x + v.y + v.z + v.w; }
  #pragma unroll
  for (int off = 1; off < 64; off <<= 1) acc += __shfl_xor(acc, off);
  if ((t & 63) == 0) dst[bid * 4 + (t >> 6)] = acc;
}

// ============================ fallback mono kernel (proven R1) ============================
__global__ __launch_bounds__(BS) void multiloss_mono(
    const float* __restrict__ loc_pred, const float* __restrict__ conf_pred,
    const float* __restrict__ targets, const float* __restrict__ default_bar,
    double* __restrict__ rloc, double* __restrict__ rconf, double* __restrict__ rnp)
{
  __shared__ float    s_lc[Dn];
  __shared__ int      s_hist[2048];
  __shared__ unsigned s_scan[BS];
  __shared__ double   s_dred[BS];
  __shared__ unsigned s_sel[2];
  __shared__ double   s_corr[2];
  __shared__ int      s_np;

  const int b = blockIdx.x;
  const int t = threadIdx.x;

  const float t0  = targets[b * 3 + 0];
  const float t1  = targets[b * 3 + 1];
  const int   lab = (int)targets[b * 3 + 2];

  const float* __restrict__ cpb = conf_pred + (size_t)b * Dn * 3;

  if (lab == 0) {
    float ce = 0.f;
    for (int d = t; d < Dn; d += BS) {
      const float* cp = cpb + d * 3;
      ce += lse3(cp[0], cp[1], cp[2]) - cp[0];
    }
    double tot = blockReduceAddD((double)ce, s_dred);
    if (t == 0) { rloc[b] = 0.0; rconf[b] = tot; rnp[b] = (double)Dn; }
    return;
  }

  const float m_c = (t0 + t1) * 0.5f;
  const float m_l = t1 - t0;

  float bestV = -1.f; int bestI = 0;
  int   nposL = 0;
  float cePosL = 0.f;
  float llocL  = 0.f;

  for (int d = t; d < Dn; d += BS) {
    float2 db = ((const float2*)default_bar)[d];
    float d_c = db.x, d_l = db.y;
    float d_s = d_c - d_l * 0.5f;
    float d_e = d_c + d_l * 0.5f;
    float inter = fmaxf(fminf(t1, d_e) - fmaxf(t0, d_s), 0.f);
    float uni = (t1 - t0) + (d_e - d_s) - inter;
    float ov  = inter / uni;

    const float* cp = cpb + d * 3;
    float c0 = cp[0];
    float lse = lse3(cp[0], cp[1], cp[2]);

    if (ov > bestV) { bestV = ov; bestI = d; }

    float lcv;
    if (ov >= 0.5f) {
      nposL++;
      float cl = (lab == 1) ? cp[1] : cp[2];
      cePosL += lse - cl;
      float2 lp = ((const float2*)loc_pred)[(size_t)b * Dn + d];
      float pd0 = lp.x - (m_c - d_c) / d_l;
      float pd1 = lp.y - __logf(m_l / d_l);
      llocL += sl1f(pd0) + sl1f(pd1);
      lcv = 0.f;
    } else {
      lcv = lse - c0;
    }
    s_lc[d] = lcv;
  }

  float* sv = (float*)s_hist;
  int*   si = (int*)(s_hist + BS);
  sv[t] = bestV; si[t] = bestI;
  __syncthreads();
  for (int off = BS >> 1; off > 0; off >>= 1) {
    if (t < off) {
      float v2 = sv[t + off]; int i2 = si[t + off];
      if (v2 > sv[t] || (v2 == sv[t] && i2 < si[t])) { sv[t] = v2; si[t] = i2; }
    }
    __syncthreads();
  }
  float bV = sv[0]; int bI = si[0];
  __syncthreads();

  double nposTot  = blockReduceAddD((double)nposL, s_dred);
  double cePosTot = blockReduceAddD((double)cePosL, s_dred);
  double llocTot  = blockReduceAddD((double)llocL, s_dred);
  int num_pos = (int)(nposTot + 0.5);

  if (t == 0) {
    double cc = 0.0, lcor = 0.0; int np2 = num_pos;
    if (bV < 0.5f) {
      int d = bI;
      const float* cp = cpb + d * 3;
      float lse = lse3(cp[0], cp[1], cp[2]);
      float cl = (lab == 1) ? cp[1] : cp[2];
      cc = (double)(lse - cl);
      float2 db = ((const float2*)default_bar)[d];
      float2 lp = ((const float2*)loc_pred)[(size_t)b * Dn + d];
      float pd0 = lp.x - (m_c - db.x) / db.y;
      float pd1 = lp.y - __logf(m_l / db.y);
      lcor = (double)(sl1f(pd0) + sl1f(pd1));
      np2 += 1;
      s_lc[d] = 0.f;
    }
    s_corr[0] = cc; s_corr[1] = lcor; s_np = np2;
  }
  __syncthreads();
  int np = s_np;
  int k  = min(3 * np, Dn - 1);

  unsigned prefix = 0;
  int K = k;
  for (int r = 0; r < 3; ++r) {
    for (int i = t; i < 2048; i += BS) s_hist[i] = 0;
    __syncthreads();
    for (int d = t; d < Dn; d += BS) {
      unsigned u = __float_as_uint(s_lc[d]);
      bool ok = (r == 0) || (r == 1 ? ((u >> 21) == prefix) : ((u >> 10) == prefix));
      if (ok) {
        unsigned bin = (r == 0) ? (u >> 21)
                     : (r == 1) ? ((u >> 10) & 0x7FFu)
                                : (u & 0x3FFu);
        atomicAdd(&s_hist[bin], 1);
      }
    }
    __syncthreads();
    int nb  = (r == 2) ? 1024 : 2048;
    int per = nb / BS;
    unsigned psum = 0;
    for (int j = 0; j < per; ++j) psum += (unsigned)s_hist[t * per + j];
    s_scan[t] = psum;
    __syncthreads();
    for (int off = 1; off < BS; off <<= 1) {
      unsigned v = (t + off < BS) ? s_scan[t + off] : 0u;
      __syncthreads();
      s_scan[t] += v;
      __syncthreads();
    }
    unsigned above = (t < BS - 1) ? s_scan[t + 1] : 0u;
    if (above < (unsigned)K && (unsigned)K <= above + psum) {
      unsigned cum = above;
      int found = 0;
      for (int j = per - 1; j >= 0; --j) {
        unsigned c = (unsigned)s_hist[t * per + j];
        if (cum + c >= (unsigned)K) { found = j; break; }
        cum += c;
      }
      s_sel[0] = (unsigned)(t * per + found);
      s_sel[1] = cum;
    }
    __syncthreads();
    unsigned selBin = s_sel[0];
    K -= (int)s_sel[1];
    prefix = (r == 0) ? selBin
           : (r == 1) ? ((prefix << 11) | selBin)
                      : ((prefix << 10) | selBin);
    __syncthreads();
  }
  const unsigned tb = prefix;

  float    ssum = 0.f;
  unsigned scnt = 0;
  for (int d = t; d < Dn; d += BS) {
    float v = s_lc[d];
    if (__float_as_uint(v) > tb) { ssum += v; scnt++; }
  }
  double S = blockReduceAddD((double)ssum, s_dred);
  double C = blockReduceAddD((double)scnt, s_dred);

  if (t == 0) {
    double tval = (double)__uint_as_float(tb);
    double topk = S + ((double)k - C) * tval;
    rloc[b]  = llocTot + s_corr[1];
    rconf[b] = cePosTot + s_corr[0] + topk;
    rnp[b]   = (double)s_np;
  }
}

// ============================ K3: final reduction ============================
__global__ __launch_bounds__(512) void multiloss_final(
    const double* __restrict__ rloc, const double* __restrict__ rconf,
    const double* __restrict__ rnp, float* __restrict__ out)
{
  __shared__ double s1[512], s2[512], s3[512];
  int t = threadIdx.x;
  s1[t] = rloc[t];
  s2[t] = rconf[t];
  s3[t] = rnp[t];
  __syncthreads();
  for (int off = 256; off > 0; off >>= 1) {
    if (t < off) { s1[t] += s1[t + off]; s2[t] += s2[t + off]; s3[t] += s3[t + off]; }
    __syncthreads();
  }
  if (t == 0) {
    double N = s3[0];
    out[0] = (float)(s1[0] / N);
    out[1] = (float)(s2[0] / N);
  }
}

extern "C" void kernel_launch(void* const* d_in, const int* in_sizes, int n_in,
                              void* d_out, int out_size, void* d_ws, size_t ws_size,
                              hipStream_t stream) {
  const float* loc_pred    = (const float*)d_in[0];
  const float* conf_pred   = (const float*)d_in[1];
  const float* targets     = (const float*)d_in[2];
  const float* default_bar = (const float*)d_in[3];
  float* out = (float*)d_out;
  char* ws = (char*)d_ws;

  constexpr size_t LC_BYTES = (size_t)Bn * Dn * sizeof(float);   // 32 MB
  constexpr size_t P_CNT = (size_t)Bn * CHUNKS;
  size_t off = LC_BYTES;
  float*  pce   = (float*)(ws + off); off += P_CNT * 4;
  float*  plloc = (float*)(ws + off); off += P_CNT * 4;
  int*    pnpos = (int*)(ws + off);   off += P_CNT * 4;
  float*  pbv   = (float*)(ws + off); off += P_CNT * 4;
  int*    pbi   = (int*)(ws + off);   off += P_CNT * 4;
  double* rloc  = (double*)(ws + off); off += Bn * 8;
  double* rconf = (double*)(ws + off); off += Bn * 8;
  double* rnp   = (double*)(ws + off); off += Bn * 8;
  float*  pr1   = (float*)(ws + off);  off += (size_t)Bn * CHUNKS * 4 * 4;
  float*  pr2   = (float*)(ws + off);  off += (size_t)Bn * CHUNKS * 4 * 4;
  const size_t NEED = off;

  if (ws_size >= NEED) {
    hipLaunchKernelGGL(multiloss_stream, dim3(Bn * CHUNKS), dim3(K1T), 0, stream,
                       loc_pred, conf_pred, targets, default_bar,
                       (float*)ws, pce, plloc, pnpos, pbv, pbi);
    hipLaunchKernelGGL(multiloss_select, dim3(Bn), dim3(BS), 0, stream,
                       loc_pred, conf_pred, targets, default_bar,
                       (const float*)ws, pce, plloc, pnpos, pbv, pbi,
                       rloc, rconf, rnp);
    hipLaunchKernelGGL(multiloss_final, dim3(1), dim3(512), 0, stream,
                       rloc, rconf, rnp, out);
    // diagnostic probes (after the real pipeline; outputs unused)
    hipLaunchKernelGGL(probe_reg12, dim3(Bn * CHUNKS), dim3(K1T), 0, stream,
                       (const float4*)conf_pred, pr1);
    hipLaunchKernelGGL(probe_dma12, dim3(Bn * CHUNKS), dim3(K1T), 0, stream,
                       (const float4*)conf_pred, pr2);
  } else {
    double* mloc  = (double*)ws;
    double* mconf = mloc + Bn;
    double* mnp   = mconf + Bn;
    hipLaunchKernelGGL(multiloss_mono, dim3(Bn), dim3(BS), 0, stream,
                       loc_pred, conf_pred, targets, default_bar, mloc, mconf, mnp);
    hipLaunchKernelGGL(multiloss_final, dim3(1), dim3(512), 0, stream,
                       mloc, mconf, mnp, out);
  }
}

// Round 8
// 88.254 us; speedup vs baseline: 1.2382x; 1.2382x over previous
//
#include <hip/hip_runtime.h>
#include <math.h>

constexpr int Bn = 512;      // batch
constexpr int Dn = 16384;    // priors
constexpr int BS = 512;      // select-kernel block size (8 waves)
constexpr int CHUNKS = 4;
constexpr int CPRI = Dn / CHUNKS;  // 4096 priors per chunk
constexpr int K1T = 256;           // stream-kernel threads

__device__ __forceinline__ float lse3(float a, float b, float c) {
  float m = fmaxf(a, fmaxf(b, c));
  return m + __logf(__expf(a - m) + __expf(b - m) + __expf(c - m));
}
__device__ __forceinline__ float sl1f(float x) {
  float a = fabsf(x);
  return a < 1.f ? 0.5f * x * x : a - 0.5f;
}

__device__ __forceinline__ double blockReduceAddD(double v, double* sred) {
  int t = threadIdx.x;
  sred[t] = v;
  __syncthreads();
  for (int off = BS >> 1; off > 0; off >>= 1) {
    if (t < off) sred[t] += sred[t + off];
    __syncthreads();
  }
  double r = sred[0];
  __syncthreads();
  return r;
}

// ============================ K1: streaming (probe_dma12 structure + compute epilogue) ============================
// Single phase: 12 back-to-back global->LDS DMA loads (48 KB = whole chunk),
// ONE barrier, then consume from LDS. This is exactly the probe structure that
// achieved >=5 TB/s; per-tile barriers / register batches all defeated MLP.
__global__ __launch_bounds__(K1T) void multiloss_stream(
    const float* __restrict__ loc_pred, const float* __restrict__ conf_pred,
    const float* __restrict__ targets, const float* __restrict__ default_bar,
    float* __restrict__ lc,
    float* __restrict__ pce, float* __restrict__ plloc, int* __restrict__ pnpos,
    float* __restrict__ pbv, int* __restrict__ pbi)
{
  __shared__ float s_conf[CPRI * 3];   // 48 KB: whole chunk
  __shared__ float s_a[4]; __shared__ float s_b[4]; __shared__ int s_c[4];
  __shared__ float s_vi[4]; __shared__ float s_vu[4]; __shared__ int s_i[4];

  const int bid = blockIdx.x;
  const int b = bid >> 2, c = bid & 3;
  const int t = threadIdx.x;

  // issue ALL 12 DMA loads back-to-back BEFORE anything else
  {
    const float4* src = (const float4*)(conf_pred + (size_t)b * Dn * 3) + (size_t)c * (CPRI * 3 / 4);
    float4* dst = (float4*)s_conf;
    const int wbase = t & ~63;
    #pragma unroll
    for (int j = 0; j < 12; ++j) {
      __builtin_amdgcn_global_load_lds(
          (const __attribute__((address_space(1))) void*)(src + j * 256 + t),
          (__attribute__((address_space(3))) void*)(dst + j * 256 + wbase),
          16, 0, 0);
    }
  }

  const float t0 = targets[b * 3 + 0];
  const float t1 = targets[b * 3 + 1];
  const int   lab = (int)targets[b * 3 + 2];

  const float2* __restrict__ bar2 = (const float2*)default_bar;
  const float2* __restrict__ lp2  = (const float2*)loc_pred + (size_t)b * Dn;
  float* __restrict__ lcrow = lc + (size_t)b * Dn;

  float ce = 0.f, lloc = 0.f; int npos = 0;
  float bInter = -1.f, bUni = 1.f; int bestI = 0;
  const float m_c = (t0 + t1) * 0.5f;
  const float m_l = t1 - t0;
  const float log_ml = __logf(m_l);

  __syncthreads();   // single drain: all 48 KB in LDS

  if (lab == 0) {
    #pragma unroll 4
    for (int i = 0; i < CPRI / K1T; ++i) {
      int p = i * K1T + t;
      float c0 = s_conf[3 * p], c1 = s_conf[3 * p + 1], c2 = s_conf[3 * p + 2];
      ce += lse3(c0, c1, c2) - c0;
    }
  } else {
    const int pbase = c * CPRI;
    #pragma unroll 4
    for (int i = 0; i < CPRI / K1T; ++i) {
      int p = i * K1T + t;
      int g = pbase + p;
      float c0 = s_conf[3 * p], c1 = s_conf[3 * p + 1], c2 = s_conf[3 * p + 2];
      float lse = lse3(c0, c1, c2);

      float2 db = bar2[g];
      float d_c = db.x, d_l = db.y;
      float d_s = d_c - d_l * 0.5f;
      float d_e = d_c + d_l * 0.5f;
      float inter = fmaxf(fminf(t1, d_e) - fmaxf(t0, d_s), 0.f);
      float uni = (t1 - t0) + (d_e - d_s) - inter;

      // argmax(inter/uni) via cross-mult (div-free, monotone in true ratio)
      float lhs = inter * bUni, rhs = bInter * uni;
      if (lhs > rhs || (lhs == rhs && g < bestI)) { bInter = inter; bUni = uni; bestI = g; }

      float lcv;
      if (2.f * inter >= uni) {   // exact sign test == (inter/uni >= 0.5)
        npos++;
        float cl = (lab == 1) ? c1 : c2;
        ce += lse - cl;
        float2 lp = lp2[g];
        float pd0 = lp.x - __fdividef(m_c - d_c, d_l);
        float pd1 = (lp.y - log_ml) + __logf(d_l);
        lloc += sl1f(pd0) + sl1f(pd1);
        lcv = 0.f;
      } else {
        lcv = lse - c0;
      }
      lcrow[g] = lcv;
    }
  }

  // wave butterfly reduce (width 64)
  #pragma unroll
  for (int off = 1; off < 64; off <<= 1) {
    ce   += __shfl_xor(ce, off);
    lloc += __shfl_xor(lloc, off);
    npos += __shfl_xor(npos, off);
    float oI = __shfl_xor(bInter, off);
    float oU = __shfl_xor(bUni, off);
    int   oX = __shfl_xor(bestI, off);
    float lhs = oI * bUni, rhs = bInter * oU;
    if (lhs > rhs || (lhs == rhs && oX < bestI)) { bInter = oI; bUni = oU; bestI = oX; }
  }
  const int w = t >> 6;
  if ((t & 63) == 0) { s_a[w] = ce; s_b[w] = lloc; s_c[w] = npos; s_vi[w] = bInter; s_vu[w] = bUni; s_i[w] = bestI; }
  __syncthreads();
  if (t == 0) {
    float Ce = s_a[0], Ll = s_b[0]; int Np = s_c[0];
    float Bi = s_vi[0], Bu = s_vu[0]; int Bx = s_i[0];
    for (int k = 1; k < 4; ++k) {
      Ce += s_a[k]; Ll += s_b[k]; Np += s_c[k];
      float lhs = s_vi[k] * Bu, rhs = Bi * s_vu[k];
      if (lhs > rhs || (lhs == rhs && s_i[k] < Bx)) { Bi = s_vi[k]; Bu = s_vu[k]; Bx = s_i[k]; }
    }
    int pidx = b * CHUNKS + c;
    pce[pidx] = Ce; plloc[pidx] = Ll; pnpos[pidx] = Np;
    pbv[pidx] = Bi / Bu;   // one exact division per chunk == ref's ov[best]
    pbi[pidx] = Bx;
  }
}

// ============================ K2: per-row select ============================
__global__ __launch_bounds__(BS) void multiloss_select(
    const float* __restrict__ loc_pred, const float* __restrict__ conf_pred,
    const float* __restrict__ targets, const float* __restrict__ default_bar,
    const float* __restrict__ lc,
    const float* __restrict__ pce, const float* __restrict__ plloc,
    const int* __restrict__ pnpos, const float* __restrict__ pbv, const int* __restrict__ pbi,
    double* __restrict__ rloc, double* __restrict__ rconf, double* __restrict__ rnp)
{
  __shared__ float    s_lc[Dn];        // 64 KB
  __shared__ int      s_hist[2048];    // 8 KB
  __shared__ double   s_dred[BS];      // 4 KB
  __shared__ unsigned s_wt[8];
  __shared__ unsigned s_sel[2];
  __shared__ double   s_sc[2];
  __shared__ int      s_np;

  const int b = blockIdx.x;
  const int t = threadIdx.x;
  const int lab = (int)targets[b * 3 + 2];

  if (lab == 0) {
    if (t == 0) {
      double ce = (double)pce[4 * b] + (double)pce[4 * b + 1]
                + (double)pce[4 * b + 2] + (double)pce[4 * b + 3];
      rloc[b] = 0.0; rconf[b] = ce; rnp[b] = (double)Dn;
    }
    return;
  }

  const float4* lcr = (const float4*)(lc + (size_t)b * Dn);
  float4* sl4 = (float4*)s_lc;
  #pragma unroll
  for (int j = 0; j < Dn / 4 / BS; ++j) sl4[j * BS + t] = lcr[j * BS + t];
  __syncthreads();

  if (t == 0) {
    const float t0 = targets[b * 3 + 0];
    const float t1 = targets[b * 3 + 1];
    double ce = 0.0, ll = 0.0; int np = 0;
    float bV = -1.f; int bI = 0;
    for (int k = 0; k < 4; ++k) {
      int pi = 4 * b + k;
      ce += (double)pce[pi]; ll += (double)plloc[pi]; np += pnpos[pi];
      float v = pbv[pi]; int i2 = pbi[pi];
      if (v > bV || (v == bV && i2 < bI)) { bV = v; bI = i2; }
    }
    if (bV < 0.5f) {
      int d = bI;
      const float* cp = conf_pred + (size_t)b * Dn * 3 + (size_t)d * 3;
      float c0 = cp[0], c1 = cp[1], c2 = cp[2];
      float lse = lse3(c0, c1, c2);
      float cl = (lab == 1) ? c1 : c2;
      ce += (double)(lse - cl);
      float2 db = ((const float2*)default_bar)[d];
      float2 lp = ((const float2*)loc_pred)[(size_t)b * Dn + d];
      float m_c = (t0 + t1) * 0.5f, m_l = t1 - t0;
      float pd0 = lp.x - (m_c - db.x) / db.y;
      float pd1 = lp.y - __logf(m_l / db.y);
      ll += (double)(sl1f(pd0) + sl1f(pd1));
      np += 1;
      s_lc[d] = 0.f;
    }
    s_sc[0] = ce; s_sc[1] = ll; s_np = np;
  }
  __syncthreads();
  const int np = s_np;
  const int k = min(3 * np, Dn - 1);

  unsigned prefix = 0;
  int K = k;
  const int lane = t & 63, w = t >> 6;
  for (int r = 0; r < 3; ++r) {
    for (int i = t; i < 2048; i += BS) s_hist[i] = 0;
    __syncthreads();
    for (int d = t; d < Dn; d += BS) {
      unsigned u = __float_as_uint(s_lc[d]);
      bool ok = (r == 0) || (r == 1 ? ((u >> 21) == prefix) : ((u >> 10) == prefix));
      if (ok) {
        unsigned bin = (r == 0) ? (u >> 21)
                     : (r == 1) ? ((u >> 10) & 0x7FFu)
                                : (u & 0x3FFu);
        atomicAdd(&s_hist[bin], 1);
      }
    }
    __syncthreads();
    const int nb  = (r == 2) ? 1024 : 2048;
    const int per = nb / BS;
    unsigned psum = 0;
    const int basebin = t * per;
    for (int j = 0; j < per; ++j) psum += (unsigned)s_hist[basebin + j];
    unsigned incl = psum;
    #pragma unroll
    for (int off = 1; off < 64; off <<= 1) {
      unsigned v = __shfl_down(incl, off, 64);
      if (lane + off < 64) incl += v;
    }
    if (lane == 0) s_wt[w] = incl;
    __syncthreads();
    unsigned aboveW = 0;
    for (int w2 = w + 1; w2 < 8; ++w2) aboveW += s_wt[w2];
    const unsigned above = aboveW + (incl - psum);
    if (above < (unsigned)K && (unsigned)K <= above + psum) {
      unsigned cum = above;
      int found = 0;
      for (int j = per - 1; j >= 0; --j) {
        unsigned cnt = (unsigned)s_hist[basebin + j];
        if (cum + cnt >= (unsigned)K) { found = j; break; }
        cum += cnt;
      }
      s_sel[0] = (unsigned)(basebin + found);
      s_sel[1] = cum;
    }
    __syncthreads();
    unsigned selBin = s_sel[0];
    K -= (int)s_sel[1];
    prefix = (r == 0) ? selBin
           : (r == 1) ? ((prefix << 11) | selBin)
                      : ((prefix << 10) | selBin);
    __syncthreads();
  }
  const unsigned tb = prefix;

  float    ssum = 0.f;
  unsigned scnt = 0;
  for (int d = t; d < Dn; d += BS) {
    float v = s_lc[d];
    if (__float_as_uint(v) > tb) { ssum += v; scnt++; }
  }
  double S = blockReduceAddD((double)ssum, s_dred);
  double C = blockReduceAddD((double)scnt, s_dred);

  if (t == 0) {
    double tval = (double)__uint_as_float(tb);
    double topk = S + ((double)k - C) * tval;
    rloc[b]  = s_sc[1];
    rconf[b] = s_sc[0] + topk;
    rnp[b]   = (double)np;
  }
}

// ============================ fallback mono kernel (proven R1) ============================
__global__ __launch_bounds__(BS) void multiloss_mono(
    const float* __restrict__ loc_pred, const float* __restrict__ conf_pred,
    const float* __restrict__ targets, const float* __restrict__ default_bar,
    double* __restrict__ rloc, double* __restrict__ rconf, double* __restrict__ rnp)
{
  __shared__ float    s_lc[Dn];
  __shared__ int      s_hist[2048];
  __shared__ unsigned s_scan[BS];
  __shared__ double   s_dred[BS];
  __shared__ unsigned s_sel[2];
  __shared__ double   s_corr[2];
  __shared__ int      s_np;

  const int b = blockIdx.x;
  const int t = threadIdx.x;

  const float t0  = targets[b * 3 + 0];
  const float t1  = targets[b * 3 + 1];
  const int   lab = (int)targets[b * 3 + 2];

  const float* __restrict__ cpb = conf_pred + (size_t)b * Dn * 3;

  if (lab == 0) {
    float ce = 0.f;
    for (int d = t; d < Dn; d += BS) {
      const float* cp = cpb + d * 3;
      ce += lse3(cp[0], cp[1], cp[2]) - cp[0];
    }
    double tot = blockReduceAddD((double)ce, s_dred);
    if (t == 0) { rloc[b] = 0.0; rconf[b] = tot; rnp[b] = (double)Dn; }
    return;
  }

  const float m_c = (t0 + t1) * 0.5f;
  const float m_l = t1 - t0;

  float bestV = -1.f; int bestI = 0;
  int   nposL = 0;
  float cePosL = 0.f;
  float llocL  = 0.f;

  for (int d = t; d < Dn; d += BS) {
    float2 db = ((const float2*)default_bar)[d];
    float d_c = db.x, d_l = db.y;
    float d_s = d_c - d_l * 0.5f;
    float d_e = d_c + d_l * 0.5f;
    float inter = fmaxf(fminf(t1, d_e) - fmaxf(t0, d_s), 0.f);
    float uni = (t1 - t0) + (d_e - d_s) - inter;
    float ov  = inter / uni;

    const float* cp = cpb + d * 3;
    float c0 = cp[0];
    float lse = lse3(cp[0], cp[1], cp[2]);

    if (ov > bestV) { bestV = ov; bestI = d; }

    float lcv;
    if (ov >= 0.5f) {
      nposL++;
      float cl = (lab == 1) ? cp[1] : cp[2];
      cePosL += lse - cl;
      float2 lp = ((const float2*)loc_pred)[(size_t)b * Dn + d];
      float pd0 = lp.x - (m_c - d_c) / d_l;
      float pd1 = lp.y - __logf(m_l / d_l);
      llocL += sl1f(pd0) + sl1f(pd1);
      lcv = 0.f;
    } else {
      lcv = lse - c0;
    }
    s_lc[d] = lcv;
  }

  float* sv = (float*)s_hist;
  int*   si = (int*)(s_hist + BS);
  sv[t] = bestV; si[t] = bestI;
  __syncthreads();
  for (int off = BS >> 1; off > 0; off >>= 1) {
    if (t < off) {
      float v2 = sv[t + off]; int i2 = si[t + off];
      if (v2 > sv[t] || (v2 == sv[t] && i2 < si[t])) { sv[t] = v2; si[t] = i2; }
    }
    __syncthreads();
  }
  float bV = sv[0]; int bI = si[0];
  __syncthreads();

  double nposTot  = blockReduceAddD((double)nposL, s_dred);
  double cePosTot = blockReduceAddD((double)cePosL, s_dred);
  double llocTot  = blockReduceAddD((double)llocL, s_dred);
  int num_pos = (int)(nposTot + 0.5);

  if (t == 0) {
    double cc = 0.0, lcor = 0.0; int np2 = num_pos;
    if (bV < 0.5f) {
      int d = bI;
      const float* cp = cpb + d * 3;
      float lse = lse3(cp[0], cp[1], cp[2]);
      float cl = (lab == 1) ? cp[1] : cp[2];
      cc = (double)(lse - cl);
      float2 db = ((const float2*)default_bar)[d];
      float2 lp = ((const float2*)loc_pred)[(size_t)b * Dn + d];
      float pd0 = lp.x - (m_c - db.x) / db.y;
      float pd1 = lp.y - __logf(m_l / db.y);
      lcor = (double)(sl1f(pd0) + sl1f(pd1));
      np2 += 1;
      s_lc[d] = 0.f;
    }
    s_corr[0] = cc; s_corr[1] = lcor; s_np = np2;
  }
  __syncthreads();
  int np = s_np;
  int k  = min(3 * np, Dn - 1);

  unsigned prefix = 0;
  int K = k;
  for (int r = 0; r < 3; ++r) {
    for (int i = t; i < 2048; i += BS) s_hist[i] = 0;
    __syncthreads();
    for (int d = t; d < Dn; d += BS) {
      unsigned u = __float_as_uint(s_lc[d]);
      bool ok = (r == 0) || (r == 1 ? ((u >> 21) == prefix) : ((u >> 10) == prefix));
      if (ok) {
        unsigned bin = (r == 0) ? (u >> 21)
                     : (r == 1) ? ((u >> 10) & 0x7FFu)
                                : (u & 0x3FFu);
        atomicAdd(&s_hist[bin], 1);
      }
    }
    __syncthreads();
    int nb  = (r == 2) ? 1024 : 2048;
    int per = nb / BS;
    unsigned psum = 0;
    for (int j = 0; j < per; ++j) psum += (unsigned)s_hist[t * per + j];
    s_scan[t] = psum;
    __syncthreads();
    for (int off = 1; off < BS; off <<= 1) {
      unsigned v = (t + off < BS) ? s_scan[t + off] : 0u;
      __syncthreads();
      s_scan[t] += v;
      __syncthreads();
    }
    unsigned above = (t < BS - 1) ? s_scan[t + 1] : 0u;
    if (above < (unsigned)K && (unsigned)K <= above + psum) {
      unsigned cum = above;
      int found = 0;
      for (int j = per - 1; j >= 0; --j) {
        unsigned c = (unsigned)s_hist[t * per + j];
        if (cum + c >= (unsigned)K) { found = j; break; }
        cum += c;
      }
      s_sel[0] = (unsigned)(t * per + found);
      s_sel[1] = cum;
    }
    __syncthreads();
    unsigned selBin = s_sel[0];
    K -= (int)s_sel[1];
    prefix = (r == 0) ? selBin
           : (r == 1) ? ((prefix << 11) | selBin)
                      : ((prefix << 10) | selBin);
    __syncthreads();
  }
  const unsigned tb = prefix;

  float    ssum = 0.f;
  unsigned scnt = 0;
  for (int d = t; d < Dn; d += BS) {
    float v = s_lc[d];
    if (__float_as_uint(v) > tb) { ssum += v; scnt++; }
  }
  double S = blockReduceAddD((double)ssum, s_dred);
  double C = blockReduceAddD((double)scnt, s_dred);

  if (t == 0) {
    double tval = (double)__uint_as_float(tb);
    double topk = S + ((double)k - C) * tval;
    rloc[b]  = llocTot + s_corr[1];
    rconf[b] = cePosTot + s_corr[0] + topk;
    rnp[b]   = (double)s_np;
  }
}

// ============================ K3: final reduction ============================
__global__ __launch_bounds__(512) void multiloss_final(
    const double* __restrict__ rloc, const double* __restrict__ rconf,
    const double* __restrict__ rnp, float* __restrict__ out)
{
  __shared__ double s1[512], s2[512], s3[512];
  int t = threadIdx.x;
  s1[t] = rloc[t];
  s2[t] = rconf[t];
  s3[t] = rnp[t];
  __syncthreads();
  for (int off = 256; off > 0; off >>= 1) {
    if (t < off) { s1[t] += s1[t + off]; s2[t] += s2[t + off]; s3[t] += s3[t + off]; }
    __syncthreads();
  }
  if (t == 0) {
    double N = s3[0];
    out[0] = (float)(s1[0] / N);
    out[1] = (float)(s2[0] / N);
  }
}

extern "C" void kernel_launch(void* const* d_in, const int* in_sizes, int n_in,
                              void* d_out, int out_size, void* d_ws, size_t ws_size,
                              hipStream_t stream) {
  const float* loc_pred    = (const float*)d_in[0];
  const float* conf_pred   = (const float*)d_in[1];
  const float* targets     = (const float*)d_in[2];
  const float* default_bar = (const float*)d_in[3];
  float* out = (float*)d_out;
  char* ws = (char*)d_ws;

  constexpr size_t LC_BYTES = (size_t)Bn * Dn * sizeof(float);   // 32 MB
  constexpr size_t P_CNT = (size_t)Bn * CHUNKS;
  size_t off = LC_BYTES;
  float*  pce   = (float*)(ws + off); off += P_CNT * 4;
  float*  plloc = (float*)(ws + off); off += P_CNT * 4;
  int*    pnpos = (int*)(ws + off);   off += P_CNT * 4;
  float*  pbv   = (float*)(ws + off); off += P_CNT * 4;
  int*    pbi   = (int*)(ws + off);   off += P_CNT * 4;
  double* rloc  = (double*)(ws + off); off += Bn * 8;
  double* rconf = (double*)(ws + off); off += Bn * 8;
  double* rnp   = (double*)(ws + off); off += Bn * 8;
  const size_t NEED = off;

  if (ws_size >= NEED) {
    hipLaunchKernelGGL(multiloss_stream, dim3(Bn * CHUNKS), dim3(K1T), 0, stream,
                       loc_pred, conf_pred, targets, default_bar,
                       (float*)ws, pce, plloc, pnpos, pbv, pbi);
    hipLaunchKernelGGL(multiloss_select, dim3(Bn), dim3(BS), 0, stream,
                       loc_pred, conf_pred, targets, default_bar,
                       (const float*)ws, pce, plloc, pnpos, pbv, pbi,
                       rloc, rconf, rnp);
    hipLaunchKernelGGL(multiloss_final, dim3(1), dim3(512), 0, stream,
                       rloc, rconf, rnp, out);
  } else {
    double* mloc  = (double*)ws;
    double* mconf = mloc + Bn;
    double* mnp   = mconf + Bn;
    hipLaunchKernelGGL(multiloss_mono, dim3(Bn), dim3(BS), 0, stream,
                       loc_pred, conf_pred, targets, default_bar, mloc, mconf, mnp);
    hipLaunchKernelGGL(multiloss_final, dim3(1), dim3(512), 0, stream,
                       mloc, mconf, mnp, out);
  }
}

// Round 9
// 74.370 us; speedup vs baseline: 1.4694x; 1.1867x over previous
//
#include <hip/hip_runtime.h>
#include <math.h>

constexpr int Bn = 512;      // batch
constexpr int Dn = 16384;    // priors
constexpr int BS = 512;      // select-kernel block size (8 waves)
constexpr int CHUNKS = 4;
constexpr int CPRI = Dn / CHUNKS;  // 4096 priors per chunk
constexpr int K1T = 256;           // stream-kernel threads

__device__ __forceinline__ float lse3(float a, float b, float c) {
  float m = fmaxf(a, fmaxf(b, c));
  return m + __logf(__expf(a - m) + __expf(b - m) + __expf(c - m));
}
__device__ __forceinline__ float sl1f(float x) {
  float a = fabsf(x);
  return a < 1.f ? 0.5f * x * x : a - 0.5f;
}

__device__ __forceinline__ double blockReduceAddD(double v, double* sred) {
  int t = threadIdx.x;
  sred[t] = v;
  __syncthreads();
  for (int off = BS >> 1; off > 0; off >>= 1) {
    if (t < off) sred[t] += sred[t + off];
    __syncthreads();
  }
  double r = sred[0];
  __syncthreads();
  return r;
}

// ============================ K1: streaming (register software-pipeline, max TLP) ============================
// No LDS staging. Each thread owns 16 priors (4 groups of 4). One-group-ahead
// register pipeline: issue next group's 5 float4 loads, sched_barrier(0) pins them
// above the current group's consume, so ~5 loads stay in flight per wave while
// 8 waves/SIMD (full residency: 8192 waves == chip capacity) cover the rest.
__global__ __launch_bounds__(K1T) void multiloss_stream(
    const float* __restrict__ loc_pred, const float* __restrict__ conf_pred,
    const float* __restrict__ targets, const float* __restrict__ default_bar,
    float* __restrict__ lc,
    float* __restrict__ pce, float* __restrict__ plloc, int* __restrict__ pnpos,
    float* __restrict__ pbv, int* __restrict__ pbi)
{
  __shared__ float s_a[4]; __shared__ float s_b[4]; __shared__ int s_c[4];
  __shared__ float s_vi[4]; __shared__ float s_vu[4]; __shared__ int s_i[4];

  const int bid = blockIdx.x;
  const int b = bid >> 2, c = bid & 3;
  const int t = threadIdx.x;

  const float t0 = targets[b * 3 + 0];
  const float t1 = targets[b * 3 + 1];
  const int   lab = (int)targets[b * 3 + 2];

  const float4* __restrict__ cp4  = (const float4*)(conf_pred + (size_t)b * Dn * 3);
  const float4* __restrict__ bar4 = (const float4*)default_bar;
  const float2* __restrict__ lp2  = (const float2*)loc_pred + (size_t)b * Dn;
  float4* __restrict__ lcrow4 = (float4*)(lc + (size_t)b * Dn);

  float ce = 0.f, lloc = 0.f; int npos = 0;
  float bInter = -1.f, bUni = 1.f; int bestI = 0;
  const float m_c = (t0 + t1) * 0.5f;
  const float m_l = t1 - t0;
  const float log_ml = (lab != 0) ? __logf(m_l) : 0.f;

  if (lab == 0) {
    // pipeline: conf only (3 loads/group)
    int q = c * 1024 + t;
    float4 A0 = cp4[3 * q], A1 = cp4[3 * q + 1], A2 = cp4[3 * q + 2];
    float4 N0, N1, N2;
    #pragma unroll
    for (int g = 0; g < 4; ++g) {
      const int qn = q + 256;
      if (g < 3) { N0 = cp4[3 * qn]; N1 = cp4[3 * qn + 1]; N2 = cp4[3 * qn + 2]; }
      __builtin_amdgcn_sched_barrier(0);
      ce += lse3(A0.x, A0.y, A0.z) - A0.x;
      ce += lse3(A0.w, A1.x, A1.y) - A0.w;
      ce += lse3(A1.z, A1.w, A2.x) - A1.z;
      ce += lse3(A2.y, A2.z, A2.w) - A2.y;
      if (g < 3) { A0 = N0; A1 = N1; A2 = N2; }
      q = qn;
    }
  } else {
    int q = c * 1024 + t;
    float4 A0 = cp4[3 * q], A1 = cp4[3 * q + 1], A2 = cp4[3 * q + 2];
    float4 Bb0 = bar4[2 * q], Bb1 = bar4[2 * q + 1];
    float4 N0, N1, N2, M0, M1;
    #pragma unroll
    for (int g = 0; g < 4; ++g) {
      const int qn = q + 256;
      if (g < 3) {
        N0 = cp4[3 * qn]; N1 = cp4[3 * qn + 1]; N2 = cp4[3 * qn + 2];
        M0 = bar4[2 * qn]; M1 = bar4[2 * qn + 1];
      }
      __builtin_amdgcn_sched_barrier(0);
      float cc[12] = {A0.x, A0.y, A0.z, A0.w, A1.x, A1.y, A1.z, A1.w, A2.x, A2.y, A2.z, A2.w};
      float bb[8]  = {Bb0.x, Bb0.y, Bb0.z, Bb0.w, Bb1.x, Bb1.y, Bb1.z, Bb1.w};
      float outv[4];
      #pragma unroll
      for (int i = 0; i < 4; ++i) {
        float d_c = bb[2 * i], d_l = bb[2 * i + 1];
        float d_s = d_c - d_l * 0.5f;
        float d_e = d_c + d_l * 0.5f;
        float inter = fmaxf(fminf(t1, d_e) - fmaxf(t0, d_s), 0.f);
        float uni = (t1 - t0) + (d_e - d_s) - inter;
        float c0 = cc[3 * i];
        float lse = lse3(cc[3 * i], cc[3 * i + 1], cc[3 * i + 2]);
        const int p = 4 * q + i;
        // argmax(inter/uni) via cross-mult (div-free, monotone in true ratio)
        float lhs = inter * bUni, rhs = bInter * uni;
        if (lhs > rhs || (lhs == rhs && p < bestI)) { bInter = inter; bUni = uni; bestI = p; }
        if (2.f * inter >= uni) {   // exact sign test == (inter/uni >= 0.5)
          npos++;
          float cl = (lab == 1) ? cc[3 * i + 1] : cc[3 * i + 2];
          ce += lse - cl;
          float2 lp = lp2[p];
          float pd0 = lp.x - __fdividef(m_c - d_c, d_l);
          float pd1 = (lp.y - log_ml) + __logf(d_l);
          lloc += sl1f(pd0) + sl1f(pd1);
          outv[i] = 0.f;
        } else {
          outv[i] = lse - c0;
        }
      }
      lcrow4[q] = make_float4(outv[0], outv[1], outv[2], outv[3]);
      if (g < 3) { A0 = N0; A1 = N1; A2 = N2; Bb0 = M0; Bb1 = M1; }
      q = qn;
    }
  }

  // wave butterfly reduce (width 64)
  #pragma unroll
  for (int off = 1; off < 64; off <<= 1) {
    ce   += __shfl_xor(ce, off);
    lloc += __shfl_xor(lloc, off);
    npos += __shfl_xor(npos, off);
    float oI = __shfl_xor(bInter, off);
    float oU = __shfl_xor(bUni, off);
    int   oX = __shfl_xor(bestI, off);
    float lhs = oI * bUni, rhs = bInter * oU;
    if (lhs > rhs || (lhs == rhs && oX < bestI)) { bInter = oI; bUni = oU; bestI = oX; }
  }
  const int w = t >> 6;
  if ((t & 63) == 0) { s_a[w] = ce; s_b[w] = lloc; s_c[w] = npos; s_vi[w] = bInter; s_vu[w] = bUni; s_i[w] = bestI; }
  __syncthreads();
  if (t == 0) {
    float Ce = s_a[0], Ll = s_b[0]; int Np = s_c[0];
    float Bi = s_vi[0], Bu = s_vu[0]; int Bx = s_i[0];
    for (int k = 1; k < 4; ++k) {
      Ce += s_a[k]; Ll += s_b[k]; Np += s_c[k];
      float lhs = s_vi[k] * Bu, rhs = Bi * s_vu[k];
      if (lhs > rhs || (lhs == rhs && s_i[k] < Bx)) { Bi = s_vi[k]; Bu = s_vu[k]; Bx = s_i[k]; }
    }
    int pidx = b * CHUNKS + c;
    pce[pidx] = Ce; plloc[pidx] = Ll; pnpos[pidx] = Np;
    pbv[pidx] = Bi / Bu;   // one exact division per chunk == ref's ov[best]
    pbi[pidx] = Bx;
  }
}

// ============================ K2: per-row select ============================
__global__ __launch_bounds__(BS) void multiloss_select(
    const float* __restrict__ loc_pred, const float* __restrict__ conf_pred,
    const float* __restrict__ targets, const float* __restrict__ default_bar,
    const float* __restrict__ lc,
    const float* __restrict__ pce, const float* __restrict__ plloc,
    const int* __restrict__ pnpos, const float* __restrict__ pbv, const int* __restrict__ pbi,
    double* __restrict__ rloc, double* __restrict__ rconf, double* __restrict__ rnp)
{
  __shared__ float    s_lc[Dn];        // 64 KB
  __shared__ int      s_hist[2048];    // 8 KB
  __shared__ double   s_dred[BS];      // 4 KB
  __shared__ unsigned s_wt[8];
  __shared__ unsigned s_sel[2];
  __shared__ double   s_sc[2];
  __shared__ int      s_np;

  const int b = blockIdx.x;
  const int t = threadIdx.x;
  const int lab = (int)targets[b * 3 + 2];

  if (lab == 0) {
    if (t == 0) {
      double ce = (double)pce[4 * b] + (double)pce[4 * b + 1]
                + (double)pce[4 * b + 2] + (double)pce[4 * b + 3];
      rloc[b] = 0.0; rconf[b] = ce; rnp[b] = (double)Dn;
    }
    return;
  }

  const float4* lcr = (const float4*)(lc + (size_t)b * Dn);
  float4* sl4 = (float4*)s_lc;
  #pragma unroll
  for (int j = 0; j < Dn / 4 / BS; ++j) sl4[j * BS + t] = lcr[j * BS + t];
  __syncthreads();

  if (t == 0) {
    const float t0 = targets[b * 3 + 0];
    const float t1 = targets[b * 3 + 1];
    double ce = 0.0, ll = 0.0; int np = 0;
    float bV = -1.f; int bI = 0;
    for (int k = 0; k < 4; ++k) {
      int pi = 4 * b + k;
      ce += (double)pce[pi]; ll += (double)plloc[pi]; np += pnpos[pi];
      float v = pbv[pi]; int i2 = pbi[pi];
      if (v > bV || (v == bV && i2 < bI)) { bV = v; bI = i2; }
    }
    if (bV < 0.5f) {
      int d = bI;
      const float* cp = conf_pred + (size_t)b * Dn * 3 + (size_t)d * 3;
      float c0 = cp[0], c1 = cp[1], c2 = cp[2];
      float lse = lse3(c0, c1, c2);
      float cl = (lab == 1) ? c1 : c2;
      ce += (double)(lse - cl);
      float2 db = ((const float2*)default_bar)[d];
      float2 lp = ((const float2*)loc_pred)[(size_t)b * Dn + d];
      float m_c = (t0 + t1) * 0.5f, m_l = t1 - t0;
      float pd0 = lp.x - (m_c - db.x) / db.y;
      float pd1 = lp.y - __logf(m_l / db.y);
      ll += (double)(sl1f(pd0) + sl1f(pd1));
      np += 1;
      s_lc[d] = 0.f;
    }
    s_sc[0] = ce; s_sc[1] = ll; s_np = np;
  }
  __syncthreads();
  const int np = s_np;
  const int k = min(3 * np, Dn - 1);

  unsigned prefix = 0;
  int K = k;
  const int lane = t & 63, w = t >> 6;
  for (int r = 0; r < 3; ++r) {
    for (int i = t; i < 2048; i += BS) s_hist[i] = 0;
    __syncthreads();
    for (int d = t; d < Dn; d += BS) {
      unsigned u = __float_as_uint(s_lc[d]);
      bool ok = (r == 0) || (r == 1 ? ((u >> 21) == prefix) : ((u >> 10) == prefix));
      if (ok) {
        unsigned bin = (r == 0) ? (u >> 21)
                     : (r == 1) ? ((u >> 10) & 0x7FFu)
                                : (u & 0x3FFu);
        atomicAdd(&s_hist[bin], 1);
      }
    }
    __syncthreads();
    const int nb  = (r == 2) ? 1024 : 2048;
    const int per = nb / BS;
    unsigned psum = 0;
    const int basebin = t * per;
    for (int j = 0; j < per; ++j) psum += (unsigned)s_hist[basebin + j];
    unsigned incl = psum;
    #pragma unroll
    for (int off = 1; off < 64; off <<= 1) {
      unsigned v = __shfl_down(incl, off, 64);
      if (lane + off < 64) incl += v;
    }
    if (lane == 0) s_wt[w] = incl;
    __syncthreads();
    unsigned aboveW = 0;
    for (int w2 = w + 1; w2 < 8; ++w2) aboveW += s_wt[w2];
    const unsigned above = aboveW + (incl - psum);
    if (above < (unsigned)K && (unsigned)K <= above + psum) {
      unsigned cum = above;
      int found = 0;
      for (int j = per - 1; j >= 0; --j) {
        unsigned cnt = (unsigned)s_hist[basebin + j];
        if (cum + cnt >= (unsigned)K) { found = j; break; }
        cum += cnt;
      }
      s_sel[0] = (unsigned)(basebin + found);
      s_sel[1] = cum;
    }
    __syncthreads();
    unsigned selBin = s_sel[0];
    K -= (int)s_sel[1];
    prefix = (r == 0) ? selBin
           : (r == 1) ? ((prefix << 11) | selBin)
                      : ((prefix << 10) | selBin);
    __syncthreads();
  }
  const unsigned tb = prefix;

  float    ssum = 0.f;
  unsigned scnt = 0;
  for (int d = t; d < Dn; d += BS) {
    float v = s_lc[d];
    if (__float_as_uint(v) > tb) { ssum += v; scnt++; }
  }
  double S = blockReduceAddD((double)ssum, s_dred);
  double C = blockReduceAddD((double)scnt, s_dred);

  if (t == 0) {
    double tval = (double)__uint_as_float(tb);
    double topk = S + ((double)k - C) * tval;
    rloc[b]  = s_sc[1];
    rconf[b] = s_sc[0] + topk;
    rnp[b]   = (double)np;
  }
}

// ============================ fallback mono kernel (proven R1) ============================
__global__ __launch_bounds__(BS) void multiloss_mono(
    const float* __restrict__ loc_pred, const float* __restrict__ conf_pred,
    const float* __restrict__ targets, const float* __restrict__ default_bar,
    double* __restrict__ rloc, double* __restrict__ rconf, double* __restrict__ rnp)
{
  __shared__ float    s_lc[Dn];
  __shared__ int      s_hist[2048];
  __shared__ unsigned s_scan[BS];
  __shared__ double   s_dred[BS];
  __shared__ unsigned s_sel[2];
  __shared__ double   s_corr[2];
  __shared__ int      s_np;

  const int b = blockIdx.x;
  const int t = threadIdx.x;

  const float t0  = targets[b * 3 + 0];
  const float t1  = targets[b * 3 + 1];
  const int   lab = (int)targets[b * 3 + 2];

  const float* __restrict__ cpb = conf_pred + (size_t)b * Dn * 3;

  if (lab == 0) {
    float ce = 0.f;
    for (int d = t; d < Dn; d += BS) {
      const float* cp = cpb + d * 3;
      ce += lse3(cp[0], cp[1], cp[2]) - cp[0];
    }
    double tot = blockReduceAddD((double)ce, s_dred);
    if (t == 0) { rloc[b] = 0.0; rconf[b] = tot; rnp[b] = (double)Dn; }
    return;
  }

  const float m_c = (t0 + t1) * 0.5f;
  const float m_l = t1 - t0;

  float bestV = -1.f; int bestI = 0;
  int   nposL = 0;
  float cePosL = 0.f;
  float llocL  = 0.f;

  for (int d = t; d < Dn; d += BS) {
    float2 db = ((const float2*)default_bar)[d];
    float d_c = db.x, d_l = db.y;
    float d_s = d_c - d_l * 0.5f;
    float d_e = d_c + d_l * 0.5f;
    float inter = fmaxf(fminf(t1, d_e) - fmaxf(t0, d_s), 0.f);
    float uni = (t1 - t0) + (d_e - d_s) - inter;
    float ov  = inter / uni;

    const float* cp = cpb + d * 3;
    float c0 = cp[0];
    float lse = lse3(cp[0], cp[1], cp[2]);

    if (ov > bestV) { bestV = ov; bestI = d; }

    float lcv;
    if (ov >= 0.5f) {
      nposL++;
      float cl = (lab == 1) ? cp[1] : cp[2];
      cePosL += lse - cl;
      float2 lp = ((const float2*)loc_pred)[(size_t)b * Dn + d];
      float pd0 = lp.x - (m_c - d_c) / d_l;
      float pd1 = lp.y - __logf(m_l / d_l);
      llocL += sl1f(pd0) + sl1f(pd1);
      lcv = 0.f;
    } else {
      lcv = lse - c0;
    }
    s_lc[d] = lcv;
  }

  float* sv = (float*)s_hist;
  int*   si = (int*)(s_hist + BS);
  sv[t] = bestV; si[t] = bestI;
  __syncthreads();
  for (int off = BS >> 1; off > 0; off >>= 1) {
    if (t < off) {
      float v2 = sv[t + off]; int i2 = si[t + off];
      if (v2 > sv[t] || (v2 == sv[t] && i2 < si[t])) { sv[t] = v2; si[t] = i2; }
    }
    __syncthreads();
  }
  float bV = sv[0]; int bI = si[0];
  __syncthreads();

  double nposTot  = blockReduceAddD((double)nposL, s_dred);
  double cePosTot = blockReduceAddD((double)cePosL, s_dred);
  double llocTot  = blockReduceAddD((double)llocL, s_dred);
  int num_pos = (int)(nposTot + 0.5);

  if (t == 0) {
    double cc = 0.0, lcor = 0.0; int np2 = num_pos;
    if (bV < 0.5f) {
      int d = bI;
      const float* cp = cpb + d * 3;
      float lse = lse3(cp[0], cp[1], cp[2]);
      float cl = (lab == 1) ? cp[1] : cp[2];
      cc = (double)(lse - cl);
      float2 db = ((const float2*)default_bar)[d];
      float2 lp = ((const float2*)loc_pred)[(size_t)b * Dn + d];
      float pd0 = lp.x - (m_c - db.x) / db.y;
      float pd1 = lp.y - __logf(m_l / db.y);
      lcor = (double)(sl1f(pd0) + sl1f(pd1));
      np2 += 1;
      s_lc[d] = 0.f;
    }
    s_corr[0] = cc; s_corr[1] = lcor; s_np = np2;
  }
  __syncthreads();
  int np = s_np;
  int k  = min(3 * np, Dn - 1);

  unsigned prefix = 0;
  int K = k;
  for (int r = 0; r < 3; ++r) {
    for (int i = t; i < 2048; i += BS) s_hist[i] = 0;
    __syncthreads();
    for (int d = t; d < Dn; d += BS) {
      unsigned u = __float_as_uint(s_lc[d]);
      bool ok = (r == 0) || (r == 1 ? ((u >> 21) == prefix) : ((u >> 10) == prefix));
      if (ok) {
        unsigned bin = (r == 0) ? (u >> 21)
                     : (r == 1) ? ((u >> 10) & 0x7FFu)
                                : (u & 0x3FFu);
        atomicAdd(&s_hist[bin], 1);
      }
    }
    __syncthreads();
    int nb  = (r == 2) ? 1024 : 2048;
    int per = nb / BS;
    unsigned psum = 0;
    for (int j = 0; j < per; ++j) psum += (unsigned)s_hist[t * per + j];
    s_scan[t] = psum;
    __syncthreads();
    for (int off = 1; off < BS; off <<= 1) {
      unsigned v = (t + off < BS) ? s_scan[t + off] : 0u;
      __syncthreads();
      s_scan[t] += v;
      __syncthreads();
    }
    unsigned above = (t < BS - 1) ? s_scan[t + 1] : 0u;
    if (above < (unsigned)K && (unsigned)K <= above + psum) {
      unsigned cum = above;
      int found = 0;
      for (int j = per - 1; j >= 0; --j) {
        unsigned c = (unsigned)s_hist[t * per + j];
        if (cum + c >= (unsigned)K) { found = j; break; }
        cum += c;
      }
      s_sel[0] = (unsigned)(t * per + found);
      s_sel[1] = cum;
    }
    __syncthreads();
    unsigned selBin = s_sel[0];
    K -= (int)s_sel[1];
    prefix = (r == 0) ? selBin
           : (r == 1) ? ((prefix << 11) | selBin)
                      : ((prefix << 10) | selBin);
    __syncthreads();
  }
  const unsigned tb = prefix;

  float    ssum = 0.f;
  unsigned scnt = 0;
  for (int d = t; d < Dn; d += BS) {
    float v = s_lc[d];
    if (__float_as_uint(v) > tb) { ssum += v; scnt++; }
  }
  double S = blockReduceAddD((double)ssum, s_dred);
  double C = blockReduceAddD((double)scnt, s_dred);

  if (t == 0) {
    double tval = (double)__uint_as_float(tb);
    double topk = S + ((double)k - C) * tval;
    rloc[b]  = llocTot + s_corr[1];
    rconf[b] = cePosTot + s_corr[0] + topk;
    rnp[b]   = (double)s_np;
  }
}

// ============================ K3: final reduction ============================
__global__ __launch_bounds__(512) void multiloss_final(
    const double* __restrict__ rloc, const double* __restrict__ rconf,
    const double* __restrict__ rnp, float* __restrict__ out)
{
  __shared__ double s1[512], s2[512], s3[512];
  int t = threadIdx.x;
  s1[t] = rloc[t];
  s2[t] = rconf[t];
  s3[t] = rnp[t];
  __syncthreads();
  for (int off = 256; off > 0; off >>= 1) {
    if (t < off) { s1[t] += s1[t + off]; s2[t] += s2[t + off]; s3[t] += s3[t + off]; }
    __syncthreads();
  }
  if (t == 0) {
    double N = s3[0];
    out[0] = (float)(s1[0] / N);
    out[1] = (float)(s2[0] / N);
  }
}

extern "C" void kernel_launch(void* const* d_in, const int* in_sizes, int n_in,
                              void* d_out, int out_size, void* d_ws, size_t ws_size,
                              hipStream_t stream) {
  const float* loc_pred    = (const float*)d_in[0];
  const float* conf_pred   = (const float*)d_in[1];
  const float* targets     = (const float*)d_in[2];
  const float* default_bar = (const float*)d_in[3];
  float* out = (float*)d_out;
  char* ws = (char*)d_ws;

  constexpr size_t LC_BYTES = (size_t)Bn * Dn * sizeof(float);   // 32 MB
  constexpr size_t P_CNT = (size_t)Bn * CHUNKS;
  size_t off = LC_BYTES;
  float*  pce   = (float*)(ws + off); off += P_CNT * 4;
  float*  plloc = (float*)(ws + off); off += P_CNT * 4;
  int*    pnpos = (int*)(ws + off);   off += P_CNT * 4;
  float*  pbv   = (float*)(ws + off); off += P_CNT * 4;
  int*    pbi   = (int*)(ws + off);   off += P_CNT * 4;
  double* rloc  = (double*)(ws + off); off += Bn * 8;
  double* rconf = (double*)(ws + off); off += Bn * 8;
  double* rnp   = (double*)(ws + off); off += Bn * 8;
  const size_t NEED = off;

  if (ws_size >= NEED) {
    hipLaunchKernelGGL(multiloss_stream, dim3(Bn * CHUNKS), dim3(K1T), 0, stream,
                       loc_pred, conf_pred, targets, default_bar,
                       (float*)ws, pce, plloc, pnpos, pbv, pbi);
    hipLaunchKernelGGL(multiloss_select, dim3(Bn), dim3(BS), 0, stream,
                       loc_pred, conf_pred, targets, default_bar,
                       (const float*)ws, pce, plloc, pnpos, pbv, pbi,
                       rloc, rconf, rnp);
    hipLaunchKernelGGL(multiloss_final, dim3(1), dim3(512), 0, stream,
                       rloc, rconf, rnp, out);
  } else {
    double* mloc  = (double*)ws;
    double* mconf = mloc + Bn;
    double* mnp   = mconf + Bn;
    hipLaunchKernelGGL(multiloss_mono, dim3(Bn), dim3(BS), 0, stream,
                       loc_pred, conf_pred, targets, default_bar, mloc, mconf, mnp);
    hipLaunchKernelGGL(multiloss_final, dim3(1), dim3(512), 0, stream,
                       mloc, mconf, mnp, out);
  }
}

// Round 10
// 65.200 us; speedup vs baseline: 1.6761x; 1.1406x over previous
//
#include <hip/hip_runtime.h>
#include <hip/hip_fp16.h>
#include <math.h>

constexpr int Bn = 512;      // batch
constexpr int Dn = 16384;    // priors
constexpr int BS = 512;      // select-kernel block size (8 waves)
constexpr int CHUNKS = 16;
constexpr int CPRI = Dn / CHUNKS;  // 1024 priors per chunk
constexpr int K1T = 256;           // stream-kernel threads

__device__ __forceinline__ float lse3(float a, float b, float c) {
  float m = fmaxf(a, fmaxf(b, c));
  return m + __logf(__expf(a - m) + __expf(b - m) + __expf(c - m));
}
__device__ __forceinline__ float sl1f(float x) {
  float a = fabsf(x);
  return a < 1.f ? 0.5f * x * x : a - 0.5f;
}

__device__ __forceinline__ double blockReduceAddD(double v, double* sred) {
  int t = threadIdx.x;
  sred[t] = v;
  __syncthreads();
  for (int off = BS >> 1; off > 0; off >>= 1) {
    if (t < off) sred[t] += sred[t + off];
    __syncthreads();
  }
  double r = sred[0];
  __syncthreads();
  return r;
}

// ============================ K1: probe-shaped streaming ============================
// Per block: 1024 priors. 5 back-to-back global->LDS DMA loads (conf 12KB + bar 8KB),
// ONE barrier, then consume entirely from LDS/registers. 7 blocks/CU co-resident:
// one block's DMA fill overlaps six others' compute. Positives handled in a sparse
// epilogue (recomputed IoU test from LDS bar; lp gather exec-masked).
__global__ __launch_bounds__(K1T) void multiloss_stream(
    const float* __restrict__ loc_pred, const float* __restrict__ conf_pred,
    const float* __restrict__ targets, const float* __restrict__ default_bar,
    unsigned short* __restrict__ lc16,
    float* __restrict__ pce, float* __restrict__ plloc, int* __restrict__ pnpos,
    float* __restrict__ pbv, int* __restrict__ pbi)
{
  __shared__ float s_conf[CPRI * 3];   // 12 KB
  __shared__ float s_bar[CPRI * 2];    // 8 KB (reused as reduce scratch at the end)

  const int bid = blockIdx.x;
  const int b = bid >> 4, c = bid & 15;
  const int t = threadIdx.x;
  const int wbase = t & ~63;

  // all 5 DMA loads back-to-back (probe structure)
  {
    const float4* srcC = (const float4*)(conf_pred + (size_t)b * Dn * 3) + (size_t)c * (CPRI * 3 / 4);
    float4* dstC = (float4*)s_conf;
    #pragma unroll
    for (int j = 0; j < 3; ++j)
      __builtin_amdgcn_global_load_lds(
          (const __attribute__((address_space(1))) void*)(srcC + j * 256 + t),
          (__attribute__((address_space(3))) void*)(dstC + j * 256 + wbase), 16, 0, 0);
    const float4* srcB = (const float4*)default_bar + (size_t)c * (CPRI * 2 / 4);
    float4* dstB = (float4*)s_bar;
    #pragma unroll
    for (int j = 0; j < 2; ++j)
      __builtin_amdgcn_global_load_lds(
          (const __attribute__((address_space(1))) void*)(srcB + j * 256 + t),
          (__attribute__((address_space(3))) void*)(dstB + j * 256 + wbase), 16, 0, 0);
  }

  const float t0  = targets[b * 3 + 0];
  const float t1  = targets[b * 3 + 1];
  const int   lab = (int)targets[b * 3 + 2];

  float ce = 0.f, lloc = 0.f; int npos = 0;
  float bInter = -1.f, bUni = 1.f; int bestI = 0;
  const float m_c = (t0 + t1) * 0.5f;
  const float m_l = t1 - t0;

  __syncthreads();   // drains all DMA (vmcnt 0)

  if (lab == 0) {
    #pragma unroll
    for (int i = 0; i < CPRI / K1T; ++i) {
      int p = i * K1T + t;
      float c0 = s_conf[3 * p], c1 = s_conf[3 * p + 1], c2 = s_conf[3 * p + 2];
      ce += lse3(c0, c1, c2) - c0;
    }
  } else {
    unsigned short* __restrict__ lcrow = lc16 + (size_t)b * Dn + (size_t)c * CPRI;
    // main loop: LDS-only inputs, fp16 lc store
    #pragma unroll
    for (int i = 0; i < CPRI / K1T; ++i) {
      int p = i * K1T + t;
      float c0 = s_conf[3 * p], c1 = s_conf[3 * p + 1], c2 = s_conf[3 * p + 2];
      float2 db = ((const float2*)s_bar)[p];
      float d_c = db.x, d_l = db.y;
      float d_s = d_c - d_l * 0.5f;
      float d_e = d_c + d_l * 0.5f;
      float inter = fmaxf(fminf(t1, d_e) - fmaxf(t0, d_s), 0.f);
      float uni = (t1 - t0) + (d_e - d_s) - inter;
      const int g = c * CPRI + p;
      float lhs = inter * bUni, rhs = bInter * uni;
      if (lhs > rhs || (lhs == rhs && g < bestI)) { bInter = inter; bUni = uni; bestI = g; }
      float lcv = (2.f * inter >= uni) ? 0.f : (lse3(c0, c1, c2) - c0);
      lcrow[p] = __half_as_ushort(__float2half(lcv));
    }
    // sparse epilogue: positives only (IoU test recomputed from LDS)
    const float log_ml = __logf(m_l);
    const float2* __restrict__ lp2 = (const float2*)loc_pred + (size_t)b * Dn + (size_t)c * CPRI;
    #pragma unroll
    for (int i = 0; i < CPRI / K1T; ++i) {
      int p = i * K1T + t;
      float2 db = ((const float2*)s_bar)[p];
      float d_c = db.x, d_l = db.y;
      float d_s = d_c - d_l * 0.5f;
      float d_e = d_c + d_l * 0.5f;
      float inter = fmaxf(fminf(t1, d_e) - fmaxf(t0, d_s), 0.f);
      float uni = (t1 - t0) + (d_e - d_s) - inter;
      if (2.f * inter >= uni) {
        npos++;
        float c0 = s_conf[3 * p], c1 = s_conf[3 * p + 1], c2 = s_conf[3 * p + 2];
        float lse = lse3(c0, c1, c2);
        float cl = (lab == 1) ? c1 : c2;
        ce += lse - cl;
        float2 lp = lp2[p];   // exec-masked sparse gather, out of the hot loop
        float pd0 = lp.x - __fdividef(m_c - d_c, d_l);
        float pd1 = (lp.y - log_ml) + __logf(d_l);
        lloc += sl1f(pd0) + sl1f(pd1);
      }
    }
  }

  // wave butterfly reduce (width 64)
  #pragma unroll
  for (int off = 1; off < 64; off <<= 1) {
    ce   += __shfl_xor(ce, off);
    lloc += __shfl_xor(lloc, off);
    npos += __shfl_xor(npos, off);
    float oI = __shfl_xor(bInter, off);
    float oU = __shfl_xor(bUni, off);
    int   oX = __shfl_xor(bestI, off);
    float lhs = oI * bUni, rhs = bInter * oU;
    if (lhs > rhs || (lhs == rhs && oX < bestI)) { bInter = oI; bUni = oU; bestI = oX; }
  }
  __syncthreads();                 // everyone done reading s_bar
  float* red = s_bar;              // reuse as scratch: 4 waves x 6 floats
  if ((t & 63) == 0) {
    int w = t >> 6;
    red[w * 6 + 0] = ce; red[w * 6 + 1] = lloc; red[w * 6 + 2] = __int_as_float(npos);
    red[w * 6 + 3] = bInter; red[w * 6 + 4] = bUni; red[w * 6 + 5] = __int_as_float(bestI);
  }
  __syncthreads();
  if (t == 0) {
    float Ce = red[0], Ll = red[1]; int Np = __float_as_int(red[2]);
    float Bi = red[3], Bu = red[4]; int Bx = __float_as_int(red[5]);
    for (int k = 1; k < 4; ++k) {
      Ce += red[k * 6 + 0]; Ll += red[k * 6 + 1]; Np += __float_as_int(red[k * 6 + 2]);
      float oI = red[k * 6 + 3], oU = red[k * 6 + 4]; int oX = __float_as_int(red[k * 6 + 5]);
      float lhs = oI * Bu, rhs = Bi * oU;
      if (lhs > rhs || (lhs == rhs && oX < Bx)) { Bi = oI; Bu = oU; Bx = oX; }
    }
    int pidx = b * CHUNKS + c;
    pce[pidx] = Ce; plloc[pidx] = Ll; pnpos[pidx] = Np;
    pbv[pidx] = Bi / Bu;   // one exact division per chunk == ref's ov[best]
    pbi[pidx] = Bx;
  }
}

// ============================ K2: per-row select (fp16, 2x8-bit radix) ============================
__global__ __launch_bounds__(BS) void multiloss_select(
    const float* __restrict__ loc_pred, const float* __restrict__ conf_pred,
    const float* __restrict__ targets, const float* __restrict__ default_bar,
    const unsigned short* __restrict__ lc16,
    const float* __restrict__ pce, const float* __restrict__ plloc,
    const int* __restrict__ pnpos, const float* __restrict__ pbv, const int* __restrict__ pbi,
    double* __restrict__ rloc, double* __restrict__ rconf, double* __restrict__ rnp)
{
  __shared__ unsigned short s_lc[Dn];  // 32 KB
  __shared__ int      s_hist[256];
  __shared__ double   s_dred[BS];      // 4 KB
  __shared__ unsigned s_wt[8];
  __shared__ unsigned s_sel[2];
  __shared__ double   s_sc[2];
  __shared__ int      s_np;

  const int b = blockIdx.x;
  const int t = threadIdx.x;
  const int lab = (int)targets[b * 3 + 2];

  if (lab == 0) {
    if (t == 0) {
      double ce = 0.0;
      for (int kk = 0; kk < CHUNKS; ++kk) ce += (double)pce[CHUNKS * b + kk];
      rloc[b] = 0.0; rconf[b] = ce; rnp[b] = (double)Dn;
    }
    return;
  }

  // load lc row into LDS (float4 = 8 halves)
  const float4* lcr = (const float4*)(lc16 + (size_t)b * Dn);
  float4* sl4 = (float4*)s_lc;
  #pragma unroll
  for (int j = 0; j < Dn / 8 / BS; ++j) sl4[j * BS + t] = lcr[j * BS + t];
  __syncthreads();

  if (t == 0) {
    const float t0 = targets[b * 3 + 0];
    const float t1 = targets[b * 3 + 1];
    double ce = 0.0, ll = 0.0; int np = 0;
    float bV = -1.f; int bI = 0;
    for (int kk = 0; kk < CHUNKS; ++kk) {
      int pi = CHUNKS * b + kk;
      ce += (double)pce[pi]; ll += (double)plloc[pi]; np += pnpos[pi];
      float v = pbv[pi]; int i2 = pbi[pi];
      if (v > bV || (v == bV && i2 < bI)) { bV = v; bI = i2; }
    }
    if (bV < 0.5f) {
      int d = bI;
      const float* cp = conf_pred + (size_t)b * Dn * 3 + (size_t)d * 3;
      float c0 = cp[0], c1 = cp[1], c2 = cp[2];
      float lse = lse3(c0, c1, c2);
      float cl = (lab == 1) ? c1 : c2;
      ce += (double)(lse - cl);
      float2 db = ((const float2*)default_bar)[d];
      float2 lp = ((const float2*)loc_pred)[(size_t)b * Dn + d];
      float m_c = (t0 + t1) * 0.5f, m_l = t1 - t0;
      float pd0 = lp.x - (m_c - db.x) / db.y;
      float pd1 = lp.y - __logf(m_l / db.y);
      ll += (double)(sl1f(pd0) + sl1f(pd1));
      np += 1;
      s_lc[d] = 0;   // forced positive leaves the negative pool
    }
    s_sc[0] = ce; s_sc[1] = ll; s_np = np;
  }
  __syncthreads();
  const int np = s_np;
  const int k = min(3 * np, Dn - 1);

  // ---- radix select on 16-bit patterns (sign always 0 -> monotone): 2 rounds of 8 bits ----
  unsigned prefix = 0;
  int K = k;
  const int lane = t & 63, w = t >> 6;
  for (int r = 0; r < 2; ++r) {
    if (t < 256) s_hist[t] = 0;
    __syncthreads();
    for (int d = t; d < Dn; d += BS) {
      unsigned u = s_lc[d];
      bool ok = (r == 0) || ((u >> 8) == prefix);
      if (ok) {
        unsigned bin = (r == 0) ? (u >> 8) : (u & 0xFFu);
        atomicAdd(&s_hist[bin], 1);
      }
    }
    __syncthreads();
    unsigned psum = (t < 256) ? (unsigned)s_hist[t] : 0u;
    unsigned incl = psum;
    #pragma unroll
    for (int off = 1; off < 64; off <<= 1) {
      unsigned v = __shfl_down(incl, off, 64);
      if (lane + off < 64) incl += v;
    }
    if (lane == 0) s_wt[w] = incl;
    __syncthreads();
    unsigned aboveW = 0;
    for (int w2 = w + 1; w2 < 8; ++w2) aboveW += s_wt[w2];
    const unsigned above = aboveW + (incl - psum);   // strict count of higher bins
    if (t < 256 && above < (unsigned)K && (unsigned)K <= above + psum) {
      s_sel[0] = (unsigned)t;
      s_sel[1] = above;
    }
    __syncthreads();
    unsigned selBin = s_sel[0];
    K -= (int)s_sel[1];
    prefix = (r == 0) ? selBin : ((prefix << 8) | selBin);
    __syncthreads();
  }
  const unsigned tb = prefix;   // 16-bit pattern of k-th largest value

  // ---- final: sum of strictly-greater + boundary ties ----
  float    ssum = 0.f;
  unsigned scnt = 0;
  for (int d = t; d < Dn; d += BS) {
    unsigned u = s_lc[d];
    if (u > tb) {
      ssum += __half2float(__ushort_as_half((unsigned short)u));
      scnt++;
    }
  }
  double S = blockReduceAddD((double)ssum, s_dred);
  double C = blockReduceAddD((double)scnt, s_dred);

  if (t == 0) {
    double tval = (double)__half2float(__ushort_as_half((unsigned short)tb));
    double topk = S + ((double)k - C) * tval;
    rloc[b]  = s_sc[1];
    rconf[b] = s_sc[0] + topk;
    rnp[b]   = (double)np;
  }
}

// ============================ fallback mono kernel (proven R1) ============================
__global__ __launch_bounds__(BS) void multiloss_mono(
    const float* __restrict__ loc_pred, const float* __restrict__ conf_pred,
    const float* __restrict__ targets, const float* __restrict__ default_bar,
    double* __restrict__ rloc, double* __restrict__ rconf, double* __restrict__ rnp)
{
  __shared__ float    s_lc[Dn];
  __shared__ int      s_hist[2048];
  __shared__ unsigned s_scan[BS];
  __shared__ double   s_dred[BS];
  __shared__ unsigned s_sel[2];
  __shared__ double   s_corr[2];
  __shared__ int      s_np;

  const int b = blockIdx.x;
  const int t = threadIdx.x;

  const float t0  = targets[b * 3 + 0];
  const float t1  = targets[b * 3 + 1];
  const int   lab = (int)targets[b * 3 + 2];

  const float* __restrict__ cpb = conf_pred + (size_t)b * Dn * 3;

  if (lab == 0) {
    float ce = 0.f;
    for (int d = t; d < Dn; d += BS) {
      const float* cp = cpb + d * 3;
      ce += lse3(cp[0], cp[1], cp[2]) - cp[0];
    }
    double tot = blockReduceAddD((double)ce, s_dred);
    if (t == 0) { rloc[b] = 0.0; rconf[b] = tot; rnp[b] = (double)Dn; }
    return;
  }

  const float m_c = (t0 + t1) * 0.5f;
  const float m_l = t1 - t0;

  float bestV = -1.f; int bestI = 0;
  int   nposL = 0;
  float cePosL = 0.f;
  float llocL  = 0.f;

  for (int d = t; d < Dn; d += BS) {
    float2 db = ((const float2*)default_bar)[d];
    float d_c = db.x, d_l = db.y;
    float d_s = d_c - d_l * 0.5f;
    float d_e = d_c + d_l * 0.5f;
    float inter = fmaxf(fminf(t1, d_e) - fmaxf(t0, d_s), 0.f);
    float uni = (t1 - t0) + (d_e - d_s) - inter;
    float ov  = inter / uni;

    const float* cp = cpb + d * 3;
    float c0 = cp[0];
    float lse = lse3(cp[0], cp[1], cp[2]);

    if (ov > bestV) { bestV = ov; bestI = d; }

    float lcv;
    if (ov >= 0.5f) {
      nposL++;
      float cl = (lab == 1) ? cp[1] : cp[2];
      cePosL += lse - cl;
      float2 lp = ((const float2*)loc_pred)[(size_t)b * Dn + d];
      float pd0 = lp.x - (m_c - d_c) / d_l;
      float pd1 = lp.y - __logf(m_l / d_l);
      llocL += sl1f(pd0) + sl1f(pd1);
      lcv = 0.f;
    } else {
      lcv = lse - c0;
    }
    s_lc[d] = lcv;
  }

  float* sv = (float*)s_hist;
  int*   si = (int*)(s_hist + BS);
  sv[t] = bestV; si[t] = bestI;
  __syncthreads();
  for (int off = BS >> 1; off > 0; off >>= 1) {
    if (t < off) {
      float v2 = sv[t + off]; int i2 = si[t + off];
      if (v2 > sv[t] || (v2 == sv[t] && i2 < si[t])) { sv[t] = v2; si[t] = i2; }
    }
    __syncthreads();
  }
  float bV = sv[0]; int bI = si[0];
  __syncthreads();

  double nposTot  = blockReduceAddD((double)nposL, s_dred);
  double cePosTot = blockReduceAddD((double)cePosL, s_dred);
  double llocTot  = blockReduceAddD((double)llocL, s_dred);
  int num_pos = (int)(nposTot + 0.5);

  if (t == 0) {
    double cc = 0.0, lcor = 0.0; int np2 = num_pos;
    if (bV < 0.5f) {
      int d = bI;
      const float* cp = cpb + d * 3;
      float lse = lse3(cp[0], cp[1], cp[2]);
      float cl = (lab == 1) ? cp[1] : cp[2];
      cc = (double)(lse - cl);
      float2 db = ((const float2*)default_bar)[d];
      float2 lp = ((const float2*)loc_pred)[(size_t)b * Dn + d];
      float pd0 = lp.x - (m_c - db.x) / db.y;
      float pd1 = lp.y - __logf(m_l / db.y);
      lcor = (double)(sl1f(pd0) + sl1f(pd1));
      np2 += 1;
      s_lc[d] = 0.f;
    }
    s_corr[0] = cc; s_corr[1] = lcor; s_np = np2;
  }
  __syncthreads();
  int np = s_np;
  int k  = min(3 * np, Dn - 1);

  unsigned prefix = 0;
  int K = k;
  for (int r = 0; r < 3; ++r) {
    for (int i = t; i < 2048; i += BS) s_hist[i] = 0;
    __syncthreads();
    for (int d = t; d < Dn; d += BS) {
      unsigned u = __float_as_uint(s_lc[d]);
      bool ok = (r == 0) || (r == 1 ? ((u >> 21) == prefix) : ((u >> 10) == prefix));
      if (ok) {
        unsigned bin = (r == 0) ? (u >> 21)
                     : (r == 1) ? ((u >> 10) & 0x7FFu)
                                : (u & 0x3FFu);
        atomicAdd(&s_hist[bin], 1);
      }
    }
    __syncthreads();
    int nb  = (r == 2) ? 1024 : 2048;
    int per = nb / BS;
    unsigned psum = 0;
    for (int j = 0; j < per; ++j) psum += (unsigned)s_hist[t * per + j];
    s_scan[t] = psum;
    __syncthreads();
    for (int off = 1; off < BS; off <<= 1) {
      unsigned v = (t + off < BS) ? s_scan[t + off] : 0u;
      __syncthreads();
      s_scan[t] += v;
      __syncthreads();
    }
    unsigned above = (t < BS - 1) ? s_scan[t + 1] : 0u;
    if (above < (unsigned)K && (unsigned)K <= above + psum) {
      unsigned cum = above;
      int found = 0;
      for (int j = per - 1; j >= 0; --j) {
        unsigned c = (unsigned)s_hist[t * per + j];
        if (cum + c >= (unsigned)K) { found = j; break; }
        cum += c;
      }
      s_sel[0] = (unsigned)(t * per + found);
      s_sel[1] = cum;
    }
    __syncthreads();
    unsigned selBin = s_sel[0];
    K -= (int)s_sel[1];
    prefix = (r == 0) ? selBin
           : (r == 1) ? ((prefix << 11) | selBin)
                      : ((prefix << 10) | selBin);
    __syncthreads();
  }
  const unsigned tb = prefix;

  float    ssum = 0.f;
  unsigned scnt = 0;
  for (int d = t; d < Dn; d += BS) {
    float v = s_lc[d];
    if (__float_as_uint(v) > tb) { ssum += v; scnt++; }
  }
  double S = blockReduceAddD((double)ssum, s_dred);
  double C = blockReduceAddD((double)scnt, s_dred);

  if (t == 0) {
    double tval = (double)__uint_as_float(tb);
    double topk = S + ((double)k - C) * tval;
    rloc[b]  = llocTot + s_corr[1];
    rconf[b] = cePosTot + s_corr[0] + topk;
    rnp[b]   = (double)s_np;
  }
}

// ============================ K3: final reduction ============================
__global__ __launch_bounds__(512) void multiloss_final(
    const double* __restrict__ rloc, const double* __restrict__ rconf,
    const double* __restrict__ rnp, float* __restrict__ out)
{
  __shared__ double s1[512], s2[512], s3[512];
  int t = threadIdx.x;
  s1[t] = rloc[t];
  s2[t] = rconf[t];
  s3[t] = rnp[t];
  __syncthreads();
  for (int off = 256; off > 0; off >>= 1) {
    if (t < off) { s1[t] += s1[t + off]; s2[t] += s2[t + off]; s3[t] += s3[t + off]; }
    __syncthreads();
  }
  if (t == 0) {
    double N = s3[0];
    out[0] = (float)(s1[0] / N);
    out[1] = (float)(s2[0] / N);
  }
}

extern "C" void kernel_launch(void* const* d_in, const int* in_sizes, int n_in,
                              void* d_out, int out_size, void* d_ws, size_t ws_size,
                              hipStream_t stream) {
  const float* loc_pred    = (const float*)d_in[0];
  const float* conf_pred   = (const float*)d_in[1];
  const float* targets     = (const float*)d_in[2];
  const float* default_bar = (const float*)d_in[3];
  float* out = (float*)d_out;
  char* ws = (char*)d_ws;

  constexpr size_t LC_BYTES = (size_t)Bn * Dn * sizeof(unsigned short);   // 16 MB
  constexpr size_t P_CNT = (size_t)Bn * CHUNKS;   // 8192
  size_t off = LC_BYTES;
  float*  pce   = (float*)(ws + off); off += P_CNT * 4;
  float*  plloc = (float*)(ws + off); off += P_CNT * 4;
  int*    pnpos = (int*)(ws + off);   off += P_CNT * 4;
  float*  pbv   = (float*)(ws + off); off += P_CNT * 4;
  int*    pbi   = (int*)(ws + off);   off += P_CNT * 4;
  double* rloc  = (double*)(ws + off); off += Bn * 8;
  double* rconf = (double*)(ws + off); off += Bn * 8;
  double* rnp   = (double*)(ws + off); off += Bn * 8;
  const size_t NEED = off;

  if (ws_size >= NEED) {
    hipLaunchKernelGGL(multiloss_stream, dim3(Bn * CHUNKS), dim3(K1T), 0, stream,
                       loc_pred, conf_pred, targets, default_bar,
                       (unsigned short*)ws, pce, plloc, pnpos, pbv, pbi);
    hipLaunchKernelGGL(multiloss_select, dim3(Bn), dim3(BS), 0, stream,
                       loc_pred, conf_pred, targets, default_bar,
                       (const unsigned short*)ws, pce, plloc, pnpos, pbv, pbi,
                       rloc, rconf, rnp);
    hipLaunchKernelGGL(multiloss_final, dim3(1), dim3(512), 0, stream,
                       rloc, rconf, rnp, out);
  } else {
    double* mloc  = (double*)ws;
    double* mconf = mloc + Bn;
    double* mnp   = mconf + Bn;
    hipLaunchKernelGGL(multiloss_mono, dim3(Bn), dim3(BS), 0, stream,
                       loc_pred, conf_pred, targets, default_bar, mloc, mconf, mnp);
    hipLaunchKernelGGL(multiloss_final, dim3(1), dim3(512), 0, stream,
                       mloc, mconf, mnp, out);
  }
}

// Round 11
// 62.054 us; speedup vs baseline: 1.7611x; 1.0507x over previous
//
#include <hip/hip_runtime.h>
#include <hip/hip_fp16.h>
#include <math.h>

constexpr int Bn = 512;      // batch
constexpr int Dn = 16384;    // priors
constexpr int BS = 512;      // select-kernel block size (8 waves)
constexpr int CHUNKS = 16;
constexpr int CPRI = Dn / CHUNKS;  // 1024 priors per chunk
constexpr int K1T = 512;           // stream-kernel threads (8 waves; 2 priors/thread)

__device__ __forceinline__ float lse3(float a, float b, float c) {
  float m = fmaxf(a, fmaxf(b, c));
  return m + __logf(__expf(a - m) + __expf(b - m) + __expf(c - m));
}
__device__ __forceinline__ float sl1f(float x) {
  float a = fabsf(x);
  return a < 1.f ? 0.5f * x * x : a - 0.5f;
}

__device__ __forceinline__ double blockReduceAddD(double v, double* sred) {
  int t = threadIdx.x;
  sred[t] = v;
  __syncthreads();
  for (int off = BS >> 1; off > 0; off >>= 1) {
    if (t < off) sred[t] += sred[t + off];
    __syncthreads();
  }
  double r = sred[0];
  __syncthreads();
  return r;
}

// ============================ K1: lean streaming ============================
// Probe-shaped staging (back-to-back DMA, one barrier), then a minimal hot loop:
// IoU (uni = T + d_l - inter), pos test, 2-exp lse, fp16 lc store, inline ce.
// NO argmax (K2 handles the rare num_pos==0 rows). Positives wave-compacted to an
// LDS list via ballot+mbcnt; each wave drains its own list (loc terms) afterwards.
__global__ __launch_bounds__(K1T) void multiloss_stream(
    const float* __restrict__ loc_pred, const float* __restrict__ conf_pred,
    const float* __restrict__ targets, const float* __restrict__ default_bar,
    unsigned short* __restrict__ lc16,
    float* __restrict__ pce, float* __restrict__ plloc, int* __restrict__ pnpos)
{
  __shared__ float s_conf[CPRI * 3];          // 12 KB
  __shared__ float s_bar[CPRI * 2];           // 8 KB
  __shared__ unsigned short s_plist[CPRI];    // 2 KB: per-wave compacted positive indices
  __shared__ float s_red[24];                 // 8 waves x 3

  const int bid = blockIdx.x;
  const int b = bid >> 4, c = bid & 15;
  const int t = threadIdx.x;
  const int l = t & 63, w = t >> 6;
  const int wb = t & ~63;    // wave-uniform f4 slot base

  // --- stage: 5 back-to-back DMA loads (conf 768 f4 + bar 512 f4), no deps ---
  {
    const float4* srcC = (const float4*)(conf_pred + (size_t)b * Dn * 3) + (size_t)c * 768;
    float4* dstC = (float4*)s_conf;
    __builtin_amdgcn_global_load_lds(
        (const __attribute__((address_space(1))) void*)(srcC + t),
        (__attribute__((address_space(3))) void*)(dstC + wb), 16, 0, 0);
    if (t < 256)
      __builtin_amdgcn_global_load_lds(
          (const __attribute__((address_space(1))) void*)(srcC + 512 + t),
          (__attribute__((address_space(3))) void*)(dstC + 512 + wb), 16, 0, 0);
    const float4* srcB = (const float4*)default_bar + (size_t)c * 512;
    float4* dstB = (float4*)s_bar;
    __builtin_amdgcn_global_load_lds(
        (const __attribute__((address_space(1))) void*)(srcB + t),
        (__attribute__((address_space(3))) void*)(dstB + wb), 16, 0, 0);
  }

  const float t0  = targets[b * 3 + 0];
  const float t1  = targets[b * 3 + 1];
  const int   lab = (int)targets[b * 3 + 2];

  float ce = 0.f, lloc = 0.f; int npos = 0;
  const float m_c = (t0 + t1) * 0.5f;
  const float m_l = t1 - t0;
  const float T   = t1 - t0;

  __syncthreads();   // drains DMA (vmcnt 0)

  if (lab == 0) {
    #pragma unroll
    for (int i = 0; i < CPRI / K1T; ++i) {
      int p = i * K1T + t;
      float c0 = s_conf[3 * p], c1 = s_conf[3 * p + 1], c2 = s_conf[3 * p + 2];
      float hi = fmaxf(c0, c1), lo = fminf(c0, c1);
      float m  = fmaxf(hi, c2), mid = fminf(hi, c2);
      float s  = 1.f + __expf(lo - m) + __expf(mid - m);
      ce += (m - c0) + __logf(s);
    }
  } else {
    unsigned short* __restrict__ lcrow = lc16 + (size_t)b * Dn + (size_t)c * CPRI;
    unsigned wcnt = 0;
    unsigned short* plist = s_plist + (w << 7);   // 128 entries per wave
    // --- hot loop: wave-segmented (wave w owns priors [128w,128w+128)) ---
    #pragma unroll
    for (int i = 0; i < 2; ++i) {
      const int p = (w << 7) + (i << 6) + l;
      float c0 = s_conf[3 * p], c1 = s_conf[3 * p + 1], c2 = s_conf[3 * p + 2];
      float2 db = ((const float2*)s_bar)[p];
      float d_c = db.x, d_l = db.y;
      float d_s = __fmaf_rn(-0.5f, d_l, d_c);
      float d_e = __fmaf_rn(0.5f, d_l, d_c);
      float inter = fmaxf(fminf(t1, d_e) - fmaxf(t0, d_s), 0.f);
      float uni = (T + d_l) - inter;            // d_e - d_s == d_l exactly
      bool pos = (2.f * inter >= uni);          // exact: == (inter/uni >= 0.5)
      npos += pos;
      float hi = fmaxf(c0, c1), lo = fminf(c0, c1);
      float m  = fmaxf(hi, c2), mid = fminf(hi, c2);
      float s  = 1.f + __expf(lo - m) + __expf(mid - m);
      float lnS = __logf(s);
      float cl = (lab == 1) ? c1 : c2;
      ce += pos ? ((m - cl) + lnS) : 0.f;
      float lcv = pos ? 0.f : ((m - c0) + lnS);
      lcrow[p] = __half_as_ushort(__float2half(lcv));
      // wave-compact positive indices
      unsigned long long mask = __ballot(pos);
      if (pos) {
        unsigned off = __builtin_amdgcn_mbcnt_hi((unsigned)(mask >> 32),
                       __builtin_amdgcn_mbcnt_lo((unsigned)mask, 0u));
        plist[wcnt + off] = (unsigned short)p;
      }
      wcnt += (unsigned)__popcll(mask);
    }
    // --- per-wave positive drain (no cross-wave sync needed) ---
    const float log_ml = __logf(m_l);
    const float2* __restrict__ lp2 = (const float2*)loc_pred + (size_t)b * Dn + (size_t)c * CPRI;
    for (unsigned j = l; j < wcnt; j += 64) {
      int p = plist[j];
      float2 db = ((const float2*)s_bar)[p];
      float2 lp = lp2[p];
      float pd0 = lp.x - __fdividef(m_c - db.x, db.y);
      float pd1 = (lp.y - log_ml) + __logf(db.y);
      lloc += sl1f(pd0) + sl1f(pd1);
    }
  }

  // wave butterfly reduce (ce, lloc, npos)
  #pragma unroll
  for (int off = 1; off < 64; off <<= 1) {
    ce   += __shfl_xor(ce, off);
    lloc += __shfl_xor(lloc, off);
    npos += __shfl_xor(npos, off);
  }
  if (l == 0) {
    s_red[w * 3 + 0] = ce; s_red[w * 3 + 1] = lloc; s_red[w * 3 + 2] = __int_as_float(npos);
  }
  __syncthreads();
  if (t == 0) {
    float Ce = 0.f, Ll = 0.f; int Np = 0;
    #pragma unroll
    for (int k = 0; k < 8; ++k) {
      Ce += s_red[k * 3 + 0]; Ll += s_red[k * 3 + 1]; Np += __float_as_int(s_red[k * 3 + 2]);
    }
    int pidx = b * CHUNKS + c;
    pce[pidx] = Ce; plloc[pidx] = Ll; pnpos[pidx] = Np;
  }
}

// ============================ K2: per-row select (fp16, 2x8-bit radix) ============================
__global__ __launch_bounds__(BS) void multiloss_select(
    const float* __restrict__ loc_pred, const float* __restrict__ conf_pred,
    const float* __restrict__ targets, const float* __restrict__ default_bar,
    const unsigned short* __restrict__ lc16,
    const float* __restrict__ pce, const float* __restrict__ plloc,
    const int* __restrict__ pnpos,
    double* __restrict__ rloc, double* __restrict__ rconf, double* __restrict__ rnp)
{
  __shared__ unsigned short s_lc[Dn];  // 32 KB
  __shared__ int      s_hist[256];
  __shared__ double   s_dred[BS];      // 4 KB
  __shared__ float    s_fv[BS];        // argmax fallback scratch
  __shared__ int      s_fi[BS];
  __shared__ unsigned s_wt[8];
  __shared__ unsigned s_sel[2];
  __shared__ double   s_sc[2];
  __shared__ int      s_np;

  const int b = blockIdx.x;
  const int t = threadIdx.x;
  const int lab = (int)targets[b * 3 + 2];

  if (lab == 0) {
    if (t == 0) {
      double ce = 0.0;
      for (int kk = 0; kk < CHUNKS; ++kk) ce += (double)pce[CHUNKS * b + kk];
      rloc[b] = 0.0; rconf[b] = ce; rnp[b] = (double)Dn;
    }
    return;
  }

  const float t0 = targets[b * 3 + 0];
  const float t1 = targets[b * 3 + 1];

  // load lc row into LDS (float4 = 8 halves)
  const float4* lcr = (const float4*)(lc16 + (size_t)b * Dn);
  float4* sl4 = (float4*)s_lc;
  #pragma unroll
  for (int j = 0; j < Dn / 8 / BS; ++j) sl4[j * BS + t] = lcr[j * BS + t];
  __syncthreads();

  if (t == 0) {
    double ce = 0.0, ll = 0.0; int np = 0;
    for (int kk = 0; kk < CHUNKS; ++kk) {
      int pi = CHUNKS * b + kk;
      ce += (double)pce[pi]; ll += (double)plloc[pi]; np += pnpos[pi];
    }
    s_sc[0] = ce; s_sc[1] = ll; s_np = np;
  }
  __syncthreads();
  int np = s_np;

  if (np == 0) {
    // rare fallback: positives = {argmax ov} only (first-max tie like reference)
    float bV = -1.f; int bI = 0;
    for (int d = t; d < Dn; d += BS) {
      float2 db = ((const float2*)default_bar)[d];
      float d_s = db.x - db.y * 0.5f;
      float d_e = db.x + db.y * 0.5f;
      float inter = fmaxf(fminf(t1, d_e) - fmaxf(t0, d_s), 0.f);
      float uni = (t1 - t0) + (d_e - d_s) - inter;
      float ov = inter / uni;          // exact, matches reference
      if (ov > bV) { bV = ov; bI = d; }   // ascending d -> first max kept per thread
    }
    s_fv[t] = bV; s_fi[t] = bI;
    __syncthreads();
    for (int off = BS >> 1; off > 0; off >>= 1) {
      if (t < off) {
        float v2 = s_fv[t + off]; int i2 = s_fi[t + off];
        if (v2 > s_fv[t] || (v2 == s_fv[t] && i2 < s_fi[t])) { s_fv[t] = v2; s_fi[t] = i2; }
      }
      __syncthreads();
    }
    if (t == 0) {
      int d = s_fi[0];
      const float* cp = conf_pred + (size_t)b * Dn * 3 + (size_t)d * 3;
      float c0 = cp[0], c1 = cp[1], c2 = cp[2];
      float lse = lse3(c0, c1, c2);
      float cl = (lab == 1) ? c1 : c2;
      float2 db = ((const float2*)default_bar)[d];
      float2 lp = ((const float2*)loc_pred)[(size_t)b * Dn + d];
      float m_c = (t0 + t1) * 0.5f, m_l = t1 - t0;
      float pd0 = lp.x - (m_c - db.x) / db.y;
      float pd1 = lp.y - __logf(m_l / db.y);
      s_sc[0] += (double)(lse - cl);
      s_sc[1] += (double)(sl1f(pd0) + sl1f(pd1));
      s_np = 1;
      s_lc[d] = 0;   // forced positive leaves the negative pool
    }
    __syncthreads();
    np = s_np;
  }
  const int k = min(3 * np, Dn - 1);

  // ---- radix select on fp16 patterns (sign always 0 -> monotone): 2 rounds of 8 bits ----
  unsigned prefix = 0;
  int K = k;
  const int lane = t & 63, w = t >> 6;
  for (int r = 0; r < 2; ++r) {
    if (t < 256) s_hist[t] = 0;
    __syncthreads();
    for (int d = t; d < Dn; d += BS) {
      unsigned u = s_lc[d];
      bool ok = (r == 0) || ((u >> 8) == prefix);
      if (ok) {
        unsigned bin = (r == 0) ? (u >> 8) : (u & 0xFFu);
        atomicAdd(&s_hist[bin], 1);
      }
    }
    __syncthreads();
    unsigned psum = (t < 256) ? (unsigned)s_hist[t] : 0u;
    unsigned incl = psum;
    #pragma unroll
    for (int off = 1; off < 64; off <<= 1) {
      unsigned v = __shfl_down(incl, off, 64);
      if (lane + off < 64) incl += v;
    }
    if (lane == 0) s_wt[w] = incl;
    __syncthreads();
    unsigned aboveW = 0;
    for (int w2 = w + 1; w2 < 8; ++w2) aboveW += s_wt[w2];
    const unsigned above = aboveW + (incl - psum);   // strict count of higher bins
    if (t < 256 && above < (unsigned)K && (unsigned)K <= above + psum) {
      s_sel[0] = (unsigned)t;
      s_sel[1] = above;
    }
    __syncthreads();
    unsigned selBin = s_sel[0];
    K -= (int)s_sel[1];
    prefix = (r == 0) ? selBin : ((prefix << 8) | selBin);
    __syncthreads();
  }
  const unsigned tb = prefix;   // 16-bit pattern of k-th largest value

  // ---- final: sum of strictly-greater + boundary ties ----
  float    ssum = 0.f;
  unsigned scnt = 0;
  for (int d = t; d < Dn; d += BS) {
    unsigned u = s_lc[d];
    if (u > tb) {
      ssum += __half2float(__ushort_as_half((unsigned short)u));
      scnt++;
    }
  }
  double S = blockReduceAddD((double)ssum, s_dred);
  double C = blockReduceAddD((double)scnt, s_dred);

  if (t == 0) {
    double tval = (double)__half2float(__ushort_as_half((unsigned short)tb));
    double topk = S + ((double)k - C) * tval;
    rloc[b]  = s_sc[1];
    rconf[b] = s_sc[0] + topk;
    rnp[b]   = (double)np;
  }
}

// ============================ fallback mono kernel (proven R1) ============================
__global__ __launch_bounds__(BS) void multiloss_mono(
    const float* __restrict__ loc_pred, const float* __restrict__ conf_pred,
    const float* __restrict__ targets, const float* __restrict__ default_bar,
    double* __restrict__ rloc, double* __restrict__ rconf, double* __restrict__ rnp)
{
  __shared__ float    s_lc[Dn];
  __shared__ int      s_hist[2048];
  __shared__ unsigned s_scan[BS];
  __shared__ double   s_dred[BS];
  __shared__ unsigned s_sel[2];
  __shared__ double   s_corr[2];
  __shared__ int      s_np;

  const int b = blockIdx.x;
  const int t = threadIdx.x;

  const float t0  = targets[b * 3 + 0];
  const float t1  = targets[b * 3 + 1];
  const int   lab = (int)targets[b * 3 + 2];

  const float* __restrict__ cpb = conf_pred + (size_t)b * Dn * 3;

  if (lab == 0) {
    float ce = 0.f;
    for (int d = t; d < Dn; d += BS) {
      const float* cp = cpb + d * 3;
      ce += lse3(cp[0], cp[1], cp[2]) - cp[0];
    }
    double tot = blockReduceAddD((double)ce, s_dred);
    if (t == 0) { rloc[b] = 0.0; rconf[b] = tot; rnp[b] = (double)Dn; }
    return;
  }

  const float m_c = (t0 + t1) * 0.5f;
  const float m_l = t1 - t0;

  float bestV = -1.f; int bestI = 0;
  int   nposL = 0;
  float cePosL = 0.f;
  float llocL  = 0.f;

  for (int d = t; d < Dn; d += BS) {
    float2 db = ((const float2*)default_bar)[d];
    float d_c = db.x, d_l = db.y;
    float d_s = d_c - d_l * 0.5f;
    float d_e = d_c + d_l * 0.5f;
    float inter = fmaxf(fminf(t1, d_e) - fmaxf(t0, d_s), 0.f);
    float uni = (t1 - t0) + (d_e - d_s) - inter;
    float ov  = inter / uni;

    const float* cp = cpb + d * 3;
    float c0 = cp[0];
    float lse = lse3(cp[0], cp[1], cp[2]);

    if (ov > bestV) { bestV = ov; bestI = d; }

    float lcv;
    if (ov >= 0.5f) {
      nposL++;
      float cl = (lab == 1) ? cp[1] : cp[2];
      cePosL += lse - cl;
      float2 lp = ((const float2*)loc_pred)[(size_t)b * Dn + d];
      float pd0 = lp.x - (m_c - d_c) / d_l;
      float pd1 = lp.y - __logf(m_l / d_l);
      llocL += sl1f(pd0) + sl1f(pd1);
      lcv = 0.f;
    } else {
      lcv = lse - c0;
    }
    s_lc[d] = lcv;
  }

  float* sv = (float*)s_hist;
  int*   si = (int*)(s_hist + BS);
  sv[t] = bestV; si[t] = bestI;
  __syncthreads();
  for (int off = BS >> 1; off > 0; off >>= 1) {
    if (t < off) {
      float v2 = sv[t + off]; int i2 = si[t + off];
      if (v2 > sv[t] || (v2 == sv[t] && i2 < si[t])) { sv[t] = v2; si[t] = i2; }
    }
    __syncthreads();
  }
  float bV = sv[0]; int bI = si[0];
  __syncthreads();

  double nposTot  = blockReduceAddD((double)nposL, s_dred);
  double cePosTot = blockReduceAddD((double)cePosL, s_dred);
  double llocTot  = blockReduceAddD((double)llocL, s_dred);
  int num_pos = (int)(nposTot + 0.5);

  if (t == 0) {
    double cc = 0.0, lcor = 0.0; int np2 = num_pos;
    if (bV < 0.5f) {
      int d = bI;
      const float* cp = cpb + d * 3;
      float lse = lse3(cp[0], cp[1], cp[2]);
      float cl = (lab == 1) ? cp[1] : cp[2];
      cc = (double)(lse - cl);
      float2 db = ((const float2*)default_bar)[d];
      float2 lp = ((const float2*)loc_pred)[(size_t)b * Dn + d];
      float pd0 = lp.x - (m_c - db.x) / db.y;
      float pd1 = lp.y - __logf(m_l / db.y);
      lcor = (double)(sl1f(pd0) + sl1f(pd1));
      np2 += 1;
      s_lc[d] = 0.f;
    }
    s_corr[0] = cc; s_corr[1] = lcor; s_np = np2;
  }
  __syncthreads();
  int np = s_np;
  int k  = min(3 * np, Dn - 1);

  unsigned prefix = 0;
  int K = k;
  for (int r = 0; r < 3; ++r) {
    for (int i = t; i < 2048; i += BS) s_hist[i] = 0;
    __syncthreads();
    for (int d = t; d < Dn; d += BS) {
      unsigned u = __float_as_uint(s_lc[d]);
      bool ok = (r == 0) || (r == 1 ? ((u >> 21) == prefix) : ((u >> 10) == prefix));
      if (ok) {
        unsigned bin = (r == 0) ? (u >> 21)
                     : (r == 1) ? ((u >> 10) & 0x7FFu)
                                : (u & 0x3FFu);
        atomicAdd(&s_hist[bin], 1);
      }
    }
    __syncthreads();
    int nb  = (r == 2) ? 1024 : 2048;
    int per = nb / BS;
    unsigned psum = 0;
    for (int j = 0; j < per; ++j) psum += (unsigned)s_hist[t * per + j];
    s_scan[t] = psum;
    __syncthreads();
    for (int off = 1; off < BS; off <<= 1) {
      unsigned v = (t + off < BS) ? s_scan[t + off] : 0u;
      __syncthreads();
      s_scan[t] += v;
      __syncthreads();
    }
    unsigned above = (t < BS - 1) ? s_scan[t + 1] : 0u;
    if (above < (unsigned)K && (unsigned)K <= above + psum) {
      unsigned cum = above;
      int found = 0;
      for (int j = per - 1; j >= 0; --j) {
        unsigned c = (unsigned)s_hist[t * per + j];
        if (cum + c >= (unsigned)K) { found = j; break; }
        cum += c;
      }
      s_sel[0] = (unsigned)(t * per + found);
      s_sel[1] = cum;
    }
    __syncthreads();
    unsigned selBin = s_sel[0];
    K -= (int)s_sel[1];
    prefix = (r == 0) ? selBin
           : (r == 1) ? ((prefix << 11) | selBin)
                      : ((prefix << 10) | selBin);
    __syncthreads();
  }
  const unsigned tb = prefix;

  float    ssum = 0.f;
  unsigned scnt = 0;
  for (int d = t; d < Dn; d += BS) {
    float v = s_lc[d];
    if (__float_as_uint(v) > tb) { ssum += v; scnt++; }
  }
  double S = blockReduceAddD((double)ssum, s_dred);
  double C = blockReduceAddD((double)scnt, s_dred);

  if (t == 0) {
    double tval = (double)__uint_as_float(tb);
    double topk = S + ((double)k - C) * tval;
    rloc[b]  = llocTot + s_corr[1];
    rconf[b] = cePosTot + s_corr[0] + topk;
    rnp[b]   = (double)s_np;
  }
}

// ============================ K3: final reduction ============================
__global__ __launch_bounds__(512) void multiloss_final(
    const double* __restrict__ rloc, const double* __restrict__ rconf,
    const double* __restrict__ rnp, float* __restrict__ out)
{
  __shared__ double s1[512], s2[512], s3[512];
  int t = threadIdx.x;
  s1[t] = rloc[t];
  s2[t] = rconf[t];
  s3[t] = rnp[t];
  __syncthreads();
  for (int off = 256; off > 0; off >>= 1) {
    if (t < off) { s1[t] += s1[t + off]; s2[t] += s2[t + off]; s3[t] += s3[t + off]; }
    __syncthreads();
  }
  if (t == 0) {
    double N = s3[0];
    out[0] = (float)(s1[0] / N);
    out[1] = (float)(s2[0] / N);
  }
}

extern "C" void kernel_launch(void* const* d_in, const int* in_sizes, int n_in,
                              void* d_out, int out_size, void* d_ws, size_t ws_size,
                              hipStream_t stream) {
  const float* loc_pred    = (const float*)d_in[0];
  const float* conf_pred   = (const float*)d_in[1];
  const float* targets     = (const float*)d_in[2];
  const float* default_bar = (const float*)d_in[3];
  float* out = (float*)d_out;
  char* ws = (char*)d_ws;

  constexpr size_t LC_BYTES = (size_t)Bn * Dn * sizeof(unsigned short);   // 16 MB
  constexpr size_t P_CNT = (size_t)Bn * CHUNKS;   // 8192
  size_t off = LC_BYTES;
  float*  pce   = (float*)(ws + off); off += P_CNT * 4;
  float*  plloc = (float*)(ws + off); off += P_CNT * 4;
  int*    pnpos = (int*)(ws + off);   off += P_CNT * 4;
  double* rloc  = (double*)(ws + off); off += Bn * 8;
  double* rconf = (double*)(ws + off); off += Bn * 8;
  double* rnp   = (double*)(ws + off); off += Bn * 8;
  const size_t NEED = off;

  if (ws_size >= NEED) {
    hipLaunchKernelGGL(multiloss_stream, dim3(Bn * CHUNKS), dim3(K1T), 0, stream,
                       loc_pred, conf_pred, targets, default_bar,
                       (unsigned short*)ws, pce, plloc, pnpos);
    hipLaunchKernelGGL(multiloss_select, dim3(Bn), dim3(BS), 0, stream,
                       loc_pred, conf_pred, targets, default_bar,
                       (const unsigned short*)ws, pce, plloc, pnpos,
                       rloc, rconf, rnp);
    hipLaunchKernelGGL(multiloss_final, dim3(1), dim3(512), 0, stream,
                       rloc, rconf, rnp, out);
  } else {
    double* mloc  = (double*)ws;
    double* mconf = mloc + Bn;
    double* mnp   = mconf + Bn;
    hipLaunchKernelGGL(multiloss_mono, dim3(Bn), dim3(BS), 0, stream,
                       loc_pred, conf_pred, targets, default_bar, mloc, mconf, mnp);
    hipLaunchKernelGGL(multiloss_final, dim3(1), dim3(512), 0, stream,
                       mloc, mconf, mnp, out);
  }
}

// Round 12
// 60.788 us; speedup vs baseline: 1.7977x; 1.0208x over previous
//
#include <hip/hip_runtime.h>
#include <hip/hip_fp16.h>
#include <math.h>

constexpr int Bn = 512;      // batch
constexpr int Dn = 16384;    // priors
constexpr int BS = 512;      // select-kernel block size (8 waves)
constexpr int CHUNKS = 32;
constexpr int CPRI = Dn / CHUNKS;  // 512 priors per chunk
constexpr int K1T = 256;           // stream-kernel threads (4 waves; 2 priors/thread)

__device__ __forceinline__ float lse3(float a, float b, float c) {
  float m = fmaxf(a, fmaxf(b, c));
  return m + __logf(__expf(a - m) + __expf(b - m) + __expf(c - m));
}
__device__ __forceinline__ float sl1f(float x) {
  float a = fabsf(x);
  return a < 1.f ? 0.5f * x * x : a - 0.5f;
}

__device__ __forceinline__ double blockReduceAddD(double v, double* sred) {
  int t = threadIdx.x;
  sred[t] = v;
  __syncthreads();
  for (int off = BS >> 1; off > 0; off >>= 1) {
    if (t < off) sred[t] += sred[t + off];
    __syncthreads();
  }
  double r = sred[0];
  __syncthreads();
  return r;
}

// ============================ K1: streaming, deep block pipeline ============================
// 16384 small blocks (512 priors, 10 KB LDS, 4 waves) -> 8 blocks/CU co-resident.
// Stage = 3 back-to-back DMA loads, ONE barrier, then a single straight-line
// consume iteration (2 priors/thread): no loops, no argmax, inline masked loc work.
// Per-block DMA drain (~10 KB) hides under 7 neighbor blocks' compute.
__global__ __launch_bounds__(K1T) void multiloss_stream(
    const float* __restrict__ loc_pred, const float* __restrict__ conf_pred,
    const float* __restrict__ targets, const float* __restrict__ default_bar,
    unsigned* __restrict__ lc32,   // packed 2xfp16 per dword
    float* __restrict__ pce, float* __restrict__ plloc, int* __restrict__ pnpos)
{
  __shared__ float s_conf[CPRI * 3];   // 6 KB
  __shared__ float s_bar[CPRI * 2];    // 4 KB
  __shared__ float s_red[12];          // 4 waves x 3

  const int bid = blockIdx.x;
  const int b = bid >> 5, c = bid & 31;
  const int t = threadIdx.x;
  const int l = t & 63, w = t >> 6;
  const int wb = t & ~63;   // wave-uniform f4 slot base

  // --- stage: 3 back-to-back DMA loads (conf 384 f4 + bar 256 f4) ---
  {
    const float4* srcC = (const float4*)(conf_pred + (size_t)b * Dn * 3) + (size_t)c * (CPRI * 3 / 4);
    float4* dstC = (float4*)s_conf;
    __builtin_amdgcn_global_load_lds(
        (const __attribute__((address_space(1))) void*)(srcC + t),
        (__attribute__((address_space(3))) void*)(dstC + wb), 16, 0, 0);
    if (t < 128)
      __builtin_amdgcn_global_load_lds(
          (const __attribute__((address_space(1))) void*)(srcC + 256 + t),
          (__attribute__((address_space(3))) void*)(dstC + 256 + wb), 16, 0, 0);
    const float4* srcB = (const float4*)default_bar + (size_t)c * (CPRI * 2 / 4);
    float4* dstB = (float4*)s_bar;
    __builtin_amdgcn_global_load_lds(
        (const __attribute__((address_space(1))) void*)(srcB + t),
        (__attribute__((address_space(3))) void*)(dstB + wb), 16, 0, 0);
  }

  const float t0  = targets[b * 3 + 0];
  const float t1  = targets[b * 3 + 1];
  const int   lab = (int)targets[b * 3 + 2];

  float ce = 0.f, lloc = 0.f; int npos = 0;
  const float m_c = (t0 + t1) * 0.5f;
  const float T   = t1 - t0;

  __syncthreads();   // drains DMA (vmcnt 0)

  // conf for priors (2t, 2t+1): 3 float2 reads at word offsets 6t,6t+2,6t+4
  const float2 ca  = ((const float2*)s_conf)[3 * t];
  const float2 cb  = ((const float2*)s_conf)[3 * t + 1];
  const float2 cc_ = ((const float2*)s_conf)[3 * t + 2];
  // prior A: (ca.x, ca.y, cb.x)   prior B: (cb.y, cc_.x, cc_.y)

  if (lab == 0) {
    {
      float hi = fmaxf(ca.x, ca.y), lo = fminf(ca.x, ca.y);
      float m  = fmaxf(hi, cb.x),  mid = fminf(hi, cb.x);
      float s  = 1.f + __expf(lo - m) + __expf(mid - m);
      ce += (m - ca.x) + __logf(s);
    }
    {
      float hi = fmaxf(cb.y, cc_.x), lo = fminf(cb.y, cc_.x);
      float m  = fmaxf(hi, cc_.y),  mid = fminf(hi, cc_.y);
      float s  = 1.f + __expf(lo - m) + __expf(mid - m);
      ce += (m - cb.y) + __logf(s);
    }
  } else {
    const float log_ml = __logf(T);
    const float2* __restrict__ lp2 = (const float2*)loc_pred + (size_t)b * Dn + (size_t)c * CPRI;
    const float4 bb = ((const float4*)s_bar)[t];   // bar A:(x,y)  bar B:(z,w)
    float lcv0, lcv1;
    const int pA = 2 * t;

    // ---- prior A ----
    {
      float dc = bb.x, dl = bb.y;
      float ds = __fmaf_rn(-0.5f, dl, dc);
      float de = __fmaf_rn(0.5f, dl, dc);
      float inter = fmaxf(fminf(t1, de) - fmaxf(t0, ds), 0.f);
      float uni = (T + dl) - inter;
      bool pos = (2.f * inter >= uni);
      float hi = fmaxf(ca.x, ca.y), lo = fminf(ca.x, ca.y);
      float m  = fmaxf(hi, cb.x),  mid = fminf(hi, cb.x);
      float s  = 1.f + __expf(lo - m) + __expf(mid - m);
      float lnS = __logf(s);
      float cl = (lab == 1) ? ca.y : cb.x;
      npos += pos;
      ce += pos ? ((m - cl) + lnS) : 0.f;
      lcv0 = pos ? 0.f : ((m - ca.x) + lnS);
      if (pos) {
        float2 lp = lp2[pA];
        float pd0 = lp.x - __fdividef(m_c - dc, dl);
        float pd1 = (lp.y - log_ml) + __logf(dl);
        lloc += sl1f(pd0) + sl1f(pd1);
      }
    }
    // ---- prior B ----
    {
      float dc = bb.z, dl = bb.w;
      float ds = __fmaf_rn(-0.5f, dl, dc);
      float de = __fmaf_rn(0.5f, dl, dc);
      float inter = fmaxf(fminf(t1, de) - fmaxf(t0, ds), 0.f);
      float uni = (T + dl) - inter;
      bool pos = (2.f * inter >= uni);
      float hi = fmaxf(cb.y, cc_.x), lo = fminf(cb.y, cc_.x);
      float m  = fmaxf(hi, cc_.y),  mid = fminf(hi, cc_.y);
      float s  = 1.f + __expf(lo - m) + __expf(mid - m);
      float lnS = __logf(s);
      float cl = (lab == 1) ? cc_.x : cc_.y;
      npos += pos;
      ce += pos ? ((m - cl) + lnS) : 0.f;
      lcv1 = pos ? 0.f : ((m - cb.y) + lnS);
      if (pos) {
        float2 lp = lp2[pA + 1];
        float pd0 = lp.x - __fdividef(m_c - dc, dl);
        float pd1 = (lp.y - log_ml) + __logf(dl);
        lloc += sl1f(pd0) + sl1f(pd1);
      }
    }
    // packed fp16 store: 1 dword/lane, fully coalesced
    __half2 hv = __floats2half2_rn(lcv0, lcv1);
    unsigned* lcrow = lc32 + ((size_t)b * Dn + (size_t)c * CPRI) / 2;
    lcrow[t] = *reinterpret_cast<unsigned*>(&hv);
  }

  // wave butterfly reduce (ce, lloc, npos)
  #pragma unroll
  for (int off = 1; off < 64; off <<= 1) {
    ce   += __shfl_xor(ce, off);
    lloc += __shfl_xor(lloc, off);
    npos += __shfl_xor(npos, off);
  }
  if (l == 0) {
    s_red[w * 3 + 0] = ce; s_red[w * 3 + 1] = lloc; s_red[w * 3 + 2] = __int_as_float(npos);
  }
  __syncthreads();
  if (t == 0) {
    float Ce = 0.f, Ll = 0.f; int Np = 0;
    #pragma unroll
    for (int k = 0; k < 4; ++k) {
      Ce += s_red[k * 3 + 0]; Ll += s_red[k * 3 + 1]; Np += __float_as_int(s_red[k * 3 + 2]);
    }
    int pidx = b * CHUNKS + c;
    pce[pidx] = Ce; plloc[pidx] = Ll; pnpos[pidx] = Np;
  }
}

// ============================ K2: per-row select (fp16, 2x8-bit radix) ============================
__global__ __launch_bounds__(BS) void multiloss_select(
    const float* __restrict__ loc_pred, const float* __restrict__ conf_pred,
    const float* __restrict__ targets, const float* __restrict__ default_bar,
    const unsigned short* __restrict__ lc16,
    const float* __restrict__ pce, const float* __restrict__ plloc,
    const int* __restrict__ pnpos,
    double* __restrict__ rloc, double* __restrict__ rconf, double* __restrict__ rnp)
{
  __shared__ unsigned short s_lc[Dn];  // 32 KB
  __shared__ int      s_hist[256];
  __shared__ double   s_dred[BS];      // 4 KB
  __shared__ float    s_fv[BS];        // argmax fallback scratch
  __shared__ int      s_fi[BS];
  __shared__ unsigned s_wt[8];
  __shared__ unsigned s_sel[2];
  __shared__ double   s_sc[2];
  __shared__ int      s_np;

  const int b = blockIdx.x;
  const int t = threadIdx.x;
  const int lab = (int)targets[b * 3 + 2];

  if (lab == 0) {
    if (t == 0) {
      double ce = 0.0;
      for (int kk = 0; kk < CHUNKS; ++kk) ce += (double)pce[CHUNKS * b + kk];
      rloc[b] = 0.0; rconf[b] = ce; rnp[b] = (double)Dn;
    }
    return;
  }

  const float t0 = targets[b * 3 + 0];
  const float t1 = targets[b * 3 + 1];

  // load lc row into LDS (float4 = 8 halves)
  const float4* lcr = (const float4*)(lc16 + (size_t)b * Dn);
  float4* sl4 = (float4*)s_lc;
  #pragma unroll
  for (int j = 0; j < Dn / 8 / BS; ++j) sl4[j * BS + t] = lcr[j * BS + t];
  __syncthreads();

  if (t == 0) {
    double ce = 0.0, ll = 0.0; int np = 0;
    for (int kk = 0; kk < CHUNKS; ++kk) {
      int pi = CHUNKS * b + kk;
      ce += (double)pce[pi]; ll += (double)plloc[pi]; np += pnpos[pi];
    }
    s_sc[0] = ce; s_sc[1] = ll; s_np = np;
  }
  __syncthreads();
  int np = s_np;

  if (np == 0) {
    // rare fallback: positives = {argmax ov} only (first-max tie like reference)
    float bV = -1.f; int bI = 0;
    for (int d = t; d < Dn; d += BS) {
      float2 db = ((const float2*)default_bar)[d];
      float d_s = db.x - db.y * 0.5f;
      float d_e = db.x + db.y * 0.5f;
      float inter = fmaxf(fminf(t1, d_e) - fmaxf(t0, d_s), 0.f);
      float uni = (t1 - t0) + (d_e - d_s) - inter;
      float ov = inter / uni;          // exact, matches reference
      if (ov > bV) { bV = ov; bI = d; }
    }
    s_fv[t] = bV; s_fi[t] = bI;
    __syncthreads();
    for (int off = BS >> 1; off > 0; off >>= 1) {
      if (t < off) {
        float v2 = s_fv[t + off]; int i2 = s_fi[t + off];
        if (v2 > s_fv[t] || (v2 == s_fv[t] && i2 < s_fi[t])) { s_fv[t] = v2; s_fi[t] = i2; }
      }
      __syncthreads();
    }
    if (t == 0) {
      int d = s_fi[0];
      const float* cp = conf_pred + (size_t)b * Dn * 3 + (size_t)d * 3;
      float c0 = cp[0], c1 = cp[1], c2 = cp[2];
      float lse = lse3(c0, c1, c2);
      float cl = (lab == 1) ? c1 : c2;
      float2 db = ((const float2*)default_bar)[d];
      float2 lp = ((const float2*)loc_pred)[(size_t)b * Dn + d];
      float m_c = (t0 + t1) * 0.5f, m_l = t1 - t0;
      float pd0 = lp.x - (m_c - db.x) / db.y;
      float pd1 = lp.y - __logf(m_l / db.y);
      s_sc[0] += (double)(lse - cl);
      s_sc[1] += (double)(sl1f(pd0) + sl1f(pd1));
      s_np = 1;
      s_lc[d] = 0;   // forced positive leaves the negative pool
    }
    __syncthreads();
    np = s_np;
  }
  const int k = min(3 * np, Dn - 1);

  // ---- radix select on fp16 patterns (sign always 0 -> monotone): 2 rounds of 8 bits ----
  unsigned prefix = 0;
  int K = k;
  const int lane = t & 63, w = t >> 6;
  for (int r = 0; r < 2; ++r) {
    if (t < 256) s_hist[t] = 0;
    __syncthreads();
    for (int d = t; d < Dn; d += BS) {
      unsigned u = s_lc[d];
      bool ok = (r == 0) || ((u >> 8) == prefix);
      if (ok) {
        unsigned bin = (r == 0) ? (u >> 8) : (u & 0xFFu);
        atomicAdd(&s_hist[bin], 1);
      }
    }
    __syncthreads();
    unsigned psum = (t < 256) ? (unsigned)s_hist[t] : 0u;
    unsigned incl = psum;
    #pragma unroll
    for (int off = 1; off < 64; off <<= 1) {
      unsigned v = __shfl_down(incl, off, 64);
      if (lane + off < 64) incl += v;
    }
    if (lane == 0) s_wt[w] = incl;
    __syncthreads();
    unsigned aboveW = 0;
    for (int w2 = w + 1; w2 < 8; ++w2) aboveW += s_wt[w2];
    const unsigned above = aboveW + (incl - psum);   // strict count of higher bins
    if (t < 256 && above < (unsigned)K && (unsigned)K <= above + psum) {
      s_sel[0] = (unsigned)t;
      s_sel[1] = above;
    }
    __syncthreads();
    unsigned selBin = s_sel[0];
    K -= (int)s_sel[1];
    prefix = (r == 0) ? selBin : ((prefix << 8) | selBin);
    __syncthreads();
  }
  const unsigned tb = prefix;   // 16-bit pattern of k-th largest value

  // ---- final: sum of strictly-greater + boundary ties ----
  float    ssum = 0.f;
  unsigned scnt = 0;
  for (int d = t; d < Dn; d += BS) {
    unsigned u = s_lc[d];
    if (u > tb) {
      ssum += __half2float(__ushort_as_half((unsigned short)u));
      scnt++;
    }
  }
  double S = blockReduceAddD((double)ssum, s_dred);
  double C = blockReduceAddD((double)scnt, s_dred);

  if (t == 0) {
    double tval = (double)__half2float(__ushort_as_half((unsigned short)tb));
    double topk = S + ((double)k - C) * tval;
    rloc[b]  = s_sc[1];
    rconf[b] = s_sc[0] + topk;
    rnp[b]   = (double)np;
  }
}

// ============================ fallback mono kernel (proven R1) ============================
__global__ __launch_bounds__(BS) void multiloss_mono(
    const float* __restrict__ loc_pred, const float* __restrict__ conf_pred,
    const float* __restrict__ targets, const float* __restrict__ default_bar,
    double* __restrict__ rloc, double* __restrict__ rconf, double* __restrict__ rnp)
{
  __shared__ float    s_lc[Dn];
  __shared__ int      s_hist[2048];
  __shared__ unsigned s_scan[BS];
  __shared__ double   s_dred[BS];
  __shared__ unsigned s_sel[2];
  __shared__ double   s_corr[2];
  __shared__ int      s_np;

  const int b = blockIdx.x;
  const int t = threadIdx.x;

  const float t0  = targets[b * 3 + 0];
  const float t1  = targets[b * 3 + 1];
  const int   lab = (int)targets[b * 3 + 2];

  const float* __restrict__ cpb = conf_pred + (size_t)b * Dn * 3;

  if (lab == 0) {
    float ce = 0.f;
    for (int d = t; d < Dn; d += BS) {
      const float* cp = cpb + d * 3;
      ce += lse3(cp[0], cp[1], cp[2]) - cp[0];
    }
    double tot = blockReduceAddD((double)ce, s_dred);
    if (t == 0) { rloc[b] = 0.0; rconf[b] = tot; rnp[b] = (double)Dn; }
    return;
  }

  const float m_c = (t0 + t1) * 0.5f;
  const float m_l = t1 - t0;

  float bestV = -1.f; int bestI = 0;
  int   nposL = 0;
  float cePosL = 0.f;
  float llocL  = 0.f;

  for (int d = t; d < Dn; d += BS) {
    float2 db = ((const float2*)default_bar)[d];
    float d_c = db.x, d_l = db.y;
    float d_s = d_c - d_l * 0.5f;
    float d_e = d_c + d_l * 0.5f;
    float inter = fmaxf(fminf(t1, d_e) - fmaxf(t0, d_s), 0.f);
    float uni = (t1 - t0) + (d_e - d_s) - inter;
    float ov  = inter / uni;

    const float* cp = cpb + d * 3;
    float c0 = cp[0];
    float lse = lse3(cp[0], cp[1], cp[2]);

    if (ov > bestV) { bestV = ov; bestI = d; }

    float lcv;
    if (ov >= 0.5f) {
      nposL++;
      float cl = (lab == 1) ? cp[1] : cp[2];
      cePosL += lse - cl;
      float2 lp = ((const float2*)loc_pred)[(size_t)b * Dn + d];
      float pd0 = lp.x - (m_c - d_c) / d_l;
      float pd1 = lp.y - __logf(m_l / d_l);
      llocL += sl1f(pd0) + sl1f(pd1);
      lcv = 0.f;
    } else {
      lcv = lse - c0;
    }
    s_lc[d] = lcv;
  }

  float* sv = (float*)s_hist;
  int*   si = (int*)(s_hist + BS);
  sv[t] = bestV; si[t] = bestI;
  __syncthreads();
  for (int off = BS >> 1; off > 0; off >>= 1) {
    if (t < off) {
      float v2 = sv[t + off]; int i2 = si[t + off];
      if (v2 > sv[t] || (v2 == sv[t] && i2 < si[t])) { sv[t] = v2; si[t] = i2; }
    }
    __syncthreads();
  }
  float bV = sv[0]; int bI = si[0];
  __syncthreads();

  double nposTot  = blockReduceAddD((double)nposL, s_dred);
  double cePosTot = blockReduceAddD((double)cePosL, s_dred);
  double llocTot  = blockReduceAddD((double)llocL, s_dred);
  int num_pos = (int)(nposTot + 0.5);

  if (t == 0) {
    double cc = 0.0, lcor = 0.0; int np2 = num_pos;
    if (bV < 0.5f) {
      int d = bI;
      const float* cp = cpb + d * 3;
      float lse = lse3(cp[0], cp[1], cp[2]);
      float cl = (lab == 1) ? cp[1] : cp[2];
      cc = (double)(lse - cl);
      float2 db = ((const float2*)default_bar)[d];
      float2 lp = ((const float2*)loc_pred)[(size_t)b * Dn + d];
      float pd0 = lp.x - (m_c - db.x) / db.y;
      float pd1 = lp.y - __logf(m_l / db.y);
      lcor = (double)(sl1f(pd0) + sl1f(pd1));
      np2 += 1;
      s_lc[d] = 0.f;
    }
    s_corr[0] = cc; s_corr[1] = lcor; s_np = np2;
  }
  __syncthreads();
  int np = s_np;
  int k  = min(3 * np, Dn - 1);

  unsigned prefix = 0;
  int K = k;
  for (int r = 0; r < 3; ++r) {
    for (int i = t; i < 2048; i += BS) s_hist[i] = 0;
    __syncthreads();
    for (int d = t; d < Dn; d += BS) {
      unsigned u = __float_as_uint(s_lc[d]);
      bool ok = (r == 0) || (r == 1 ? ((u >> 21) == prefix) : ((u >> 10) == prefix));
      if (ok) {
        unsigned bin = (r == 0) ? (u >> 21)
                     : (r == 1) ? ((u >> 10) & 0x7FFu)
                                : (u & 0x3FFu);
        atomicAdd(&s_hist[bin], 1);
      }
    }
    __syncthreads();
    int nb  = (r == 2) ? 1024 : 2048;
    int per = nb / BS;
    unsigned psum = 0;
    for (int j = 0; j < per; ++j) psum += (unsigned)s_hist[t * per + j];
    s_scan[t] = psum;
    __syncthreads();
    for (int off = 1; off < BS; off <<= 1) {
      unsigned v = (t + off < BS) ? s_scan[t + off] : 0u;
      __syncthreads();
      s_scan[t] += v;
      __syncthreads();
    }
    unsigned above = (t < BS - 1) ? s_scan[t + 1] : 0u;
    if (above < (unsigned)K && (unsigned)K <= above + psum) {
      unsigned cum = above;
      int found = 0;
      for (int j = per - 1; j >= 0; --j) {
        unsigned c = (unsigned)s_hist[t * per + j];
        if (cum + c >= (unsigned)K) { found = j; break; }
        cum += c;
      }
      s_sel[0] = (unsigned)(t * per + found);
      s_sel[1] = cum;
    }
    __syncthreads();
    unsigned selBin = s_sel[0];
    K -= (int)s_sel[1];
    prefix = (r == 0) ? selBin
           : (r == 1) ? ((prefix << 11) | selBin)
                      : ((prefix << 10) | selBin);
    __syncthreads();
  }
  const unsigned tb = prefix;

  float    ssum = 0.f;
  unsigned scnt = 0;
  for (int d = t; d < Dn; d += BS) {
    float v = s_lc[d];
    if (__float_as_uint(v) > tb) { ssum += v; scnt++; }
  }
  double S = blockReduceAddD((double)ssum, s_dred);
  double C = blockReduceAddD((double)scnt, s_dred);

  if (t == 0) {
    double tval = (double)__uint_as_float(tb);
    double topk = S + ((double)k - C) * tval;
    rloc[b]  = llocTot + s_corr[1];
    rconf[b] = cePosTot + s_corr[0] + topk;
    rnp[b]   = (double)s_np;
  }
}

// ============================ K3: final reduction ============================
__global__ __launch_bounds__(512) void multiloss_final(
    const double* __restrict__ rloc, const double* __restrict__ rconf,
    const double* __restrict__ rnp, float* __restrict__ out)
{
  __shared__ double s1[512], s2[512], s3[512];
  int t = threadIdx.x;
  s1[t] = rloc[t];
  s2[t] = rconf[t];
  s3[t] = rnp[t];
  __syncthreads();
  for (int off = 256; off > 0; off >>= 1) {
    if (t < off) { s1[t] += s1[t + off]; s2[t] += s2[t + off]; s3[t] += s3[t + off]; }
    __syncthreads();
  }
  if (t == 0) {
    double N = s3[0];
    out[0] = (float)(s1[0] / N);
    out[1] = (float)(s2[0] / N);
  }
}

extern "C" void kernel_launch(void* const* d_in, const int* in_sizes, int n_in,
                              void* d_out, int out_size, void* d_ws, size_t ws_size,
                              hipStream_t stream) {
  const float* loc_pred    = (const float*)d_in[0];
  const float* conf_pred   = (const float*)d_in[1];
  const float* targets     = (const float*)d_in[2];
  const float* default_bar = (const float*)d_in[3];
  float* out = (float*)d_out;
  char* ws = (char*)d_ws;

  constexpr size_t LC_BYTES = (size_t)Bn * Dn * sizeof(unsigned short);   // 16 MB
  constexpr size_t P_CNT = (size_t)Bn * CHUNKS;   // 16384
  size_t off = LC_BYTES;
  float*  pce   = (float*)(ws + off); off += P_CNT * 4;
  float*  plloc = (float*)(ws + off); off += P_CNT * 4;
  int*    pnpos = (int*)(ws + off);   off += P_CNT * 4;
  double* rloc  = (double*)(ws + off); off += Bn * 8;
  double* rconf = (double*)(ws + off); off += Bn * 8;
  double* rnp   = (double*)(ws + off); off += Bn * 8;
  const size_t NEED = off;

  if (ws_size >= NEED) {
    hipLaunchKernelGGL(multiloss_stream, dim3(Bn * CHUNKS), dim3(K1T), 0, stream,
                       loc_pred, conf_pred, targets, default_bar,
                       (unsigned*)ws, pce, plloc, pnpos);
    hipLaunchKernelGGL(multiloss_select, dim3(Bn), dim3(BS), 0, stream,
                       loc_pred, conf_pred, targets, default_bar,
                       (const unsigned short*)ws, pce, plloc, pnpos,
                       rloc, rconf, rnp);
    hipLaunchKernelGGL(multiloss_final, dim3(1), dim3(512), 0, stream,
                       rloc, rconf, rnp, out);
  } else {
    double* mloc  = (double*)ws;
    double* mconf = mloc + Bn;
    double* mnp   = mconf + Bn;
    hipLaunchKernelGGL(multiloss_mono, dim3(Bn), dim3(BS), 0, stream,
                       loc_pred, conf_pred, targets, default_bar, mloc, mconf, mnp);
    hipLaunchKernelGGL(multiloss_final, dim3(1), dim3(512), 0, stream,
                       mloc, mconf, mnp, out);
  }
}